// Round 2
// baseline (3924.422 us; speedup 1.0000x reference)
//
#include <hip/hip_runtime.h>
#include <hip/hip_bf16.h>
#include <math.h>

// Model dims
#define DV   32000
#define DM   1024
#define DMLP 4096
#define DH   64
#define NH   16
#define NL   4
#define BATCH 2
#define S    2048
#define MTOK (BATCH*S)   // 4096 tokens
#define CH   8           // heads per attention chunk

typedef __bf16 bf16_t;
typedef bf16_t bf16x8 __attribute__((ext_vector_type(8)));
typedef float  f32x4  __attribute__((ext_vector_type(4)));

#define AS1 __attribute__((address_space(1)))
#define AS3 __attribute__((address_space(3)))

__device__ __forceinline__ void gload16(const bf16_t* g, bf16_t* l) {
    __builtin_amdgcn_global_load_lds((const AS1 void*)g, (AS3 void*)l, 16, 0, 0);
}

// ---------------------------------------------------------------------------
// Generic TN GEMM: C[M,N] = A[M,K] * B[N,K]^T, bf16 in, f32 accum.
// Grid: (M/BM, N/BN, Z)  -- M on x so consecutive blocks share the B panel.
// LDS layout: [BK/8][rows][8] (K-major chunks) -> linear global_load_lds dest
// AND conflict-free ds_read_b128 fragment reads.
// MODE 0: write bf16 (optional bias/relu)
// MODE 1: write f32  (optional bias)
// MODE 2: residual add: resid_f32 += acc(+bias); residb_bf16 = bf16(resid)
// CAUSAL 0: none; 1: skip fully-masked key tiles (scores GEMM);
//        2: truncate K-loop at causal boundary (PV GEMM)
// ---------------------------------------------------------------------------
template<int BM, int BN, int MODE, bool BIAS, bool RELU, int CAUSAL>
__global__ __launch_bounds__(256)
void gemm_tn(const bf16_t* __restrict__ A, long sA,
             const bf16_t* __restrict__ Bm, long sB,
             char* __restrict__ Out, long sC, int ldc,
             const float* __restrict__ bias,
             float* __restrict__ resid, bf16_t* __restrict__ residb,
             int K)
{
    constexpr int BK = 32;
    constexpr int WM = BM/2, WN = BN/2;
    constexpr int FM = WM/16, FN = WN/16;
    constexpr int APASS = (BM*BK*2)/(256*16);
    constexpr int BPASS = (BN*BK*2)/(256*16);

    const int mb = blockIdx.x, nb = blockIdx.y;
    if (CAUSAL == 1 && nb*BN >= mb*BM + BM) return;   // fully-masked tile

    __shared__ alignas(16) bf16_t As[BM*BK];
    __shared__ alignas(16) bf16_t Bs[BN*BK];

    const int tid  = threadIdx.x;
    const int wave = tid >> 6, lane = tid & 63;
    const int wm = wave >> 1, wn = wave & 1;
    const int l16 = lane & 15, lh = lane >> 4;
    const long z = blockIdx.z;

    const bf16_t* Ab = A  + z*sA + (long)mb*BM*K;
    const bf16_t* Bb = Bm + z*sB + (long)nb*BN*K;

    f32x4 acc[FM][FN];
#pragma unroll
    for (int i=0;i<FM;i++)
#pragma unroll
        for (int j=0;j<FN;j++) { f32x4 zv = {0.f,0.f,0.f,0.f}; acc[i][j] = zv; }

    int Kend = (CAUSAL == 2) ? ((mb+1)*BM < K ? (mb+1)*BM : K) : K;

    for (int k0 = 0; k0 < Kend; k0 += BK) {
        __syncthreads();   // all waves done reading previous tile
        // stage A tile: chunk c -> LDS [c*16B], src row = c%BM, kh = c/BM
#pragma unroll
        for (int u=0; u<APASS; ++u) {
            int c = u*256 + tid;
            int kh = c / BM, row = c % BM;
            gload16(&Ab[(long)row*K + k0 + kh*8], &As[c*8]);
        }
#pragma unroll
        for (int u=0; u<BPASS; ++u) {
            int c = u*256 + tid;
            int kh = c / BN, row = c % BN;
            gload16(&Bb[(long)row*K + k0 + kh*8], &Bs[c*8]);
        }
        __syncthreads();   // vmcnt(0) drain + barrier

        bf16x8 af[FM], bfr[FN];
#pragma unroll
        for (int i=0;i<FM;i++)
            af[i]  = *(const bf16x8*)&As[(lh*BM + wm*WM + i*16 + l16)*8];
#pragma unroll
        for (int j=0;j<FN;j++)
            bfr[j] = *(const bf16x8*)&Bs[(lh*BN + wn*WN + j*16 + l16)*8];
#pragma unroll
        for (int i=0;i<FM;i++)
#pragma unroll
            for (int j=0;j<FN;j++)
                acc[i][j] = __builtin_amdgcn_mfma_f32_16x16x32_bf16(af[i], bfr[j], acc[i][j], 0,0,0);
    }

    // epilogue: C/D layout col=lane&15, row=(lane>>4)*4+reg  [measured m89/m91]
#pragma unroll
    for (int i=0;i<FM;i++) {
        int row0 = mb*BM + wm*WM + i*16 + lh*4;
#pragma unroll
        for (int j=0;j<FN;j++) {
            int col = nb*BN + wn*WN + j*16 + l16;
            float bv = BIAS ? bias[col] : 0.0f;
#pragma unroll
            for (int r=0;r<4;r++) {
                int row = row0 + r;
                float v = acc[i][j][r] + bv;
                if (RELU) v = v > 0.f ? v : 0.f;
                if constexpr (MODE == 0) {
                    long off = z*sC + (long)row*ldc + col;
                    ((bf16_t*)Out)[off] = (bf16_t)v;
                } else if constexpr (MODE == 1) {
                    long off = z*sC + (long)row*ldc + col;
                    ((float*)Out)[off] = v;
                } else {
                    long o2 = (long)row*ldc + col;
                    float nv = resid[o2] + v;
                    resid[o2]  = nv;
                    residb[o2] = (bf16_t)nv;
                }
            }
        }
    }
}

// ---------------------------------------------------------------------------
// Weight conversion kernels
// ---------------------------------------------------------------------------
__global__ __launch_bounds__(256) void k_conv_qkv(
    const float* __restrict__ Wq, const float* __restrict__ Wk,
    const float* __restrict__ Wv, bf16_t* __restrict__ out)
{
    long idx = (long)blockIdx.x*256 + threadIdx.x;   // NL*3072*DM total
    long l = idx / (3072L*DM);
    long r = idx % (3072L*DM);
    int row = (int)(r / DM), d = (int)(r % DM);
    int sel = row >> 10, rr = row & 1023;
    const float* src = sel==0 ? Wq : (sel==1 ? Wk : Wv);
    out[idx] = (bf16_t)src[(l*1024 + rr)*(long)DM + d];
}

__global__ __launch_bounds__(256) void k_conv(const float* __restrict__ src,
                                              bf16_t* __restrict__ dst, long n)
{
    long i = ((long)blockIdx.x*256 + threadIdx.x)*4;
    if (i >= n) return;
    float4 v = *(const float4*)&src[i];
    dst[i+0]=(bf16_t)v.x; dst[i+1]=(bf16_t)v.y; dst[i+2]=(bf16_t)v.z; dst[i+3]=(bf16_t)v.w;
}

// W_U [DM][DV] -> WUt [DV][DM] bf16 (tiled transpose)
__global__ __launch_bounds__(256) void k_trans_wu(const float* __restrict__ W,
                                                  bf16_t* __restrict__ out)
{
    __shared__ float tile[32][33];
    int n0 = blockIdx.x*32, k0 = blockIdx.y*32;
    int tx = threadIdx.x & 31, ty = threadIdx.x >> 5;   // ty 0..7
#pragma unroll
    for (int u=0;u<4;u++)
        tile[ty+u*8][tx] = W[(long)(k0+ty+u*8)*DV + n0+tx];
    __syncthreads();
#pragma unroll
    for (int u=0;u<4;u++)
        out[(long)(n0+ty+u*8)*DM + k0+tx] = (bf16_t)tile[tx][ty+u*8];
}

// ---------------------------------------------------------------------------
// Embedding: x[b,p,d] = W_E[d, tok[b,p]] + W_pos[p,d]
// ---------------------------------------------------------------------------
__global__ __launch_bounds__(256) void k_embed(const int* __restrict__ tok,
    const float* __restrict__ WE, const float* __restrict__ Wpos,
    float* __restrict__ xf, bf16_t* __restrict__ xb)
{
    int bp = blockIdx.x;
    int p  = bp & (S-1);
    int t  = tok[bp];
#pragma unroll
    for (int u=0;u<4;u++) {
        int d = u*256 + threadIdx.x;
        float v = WE[(long)d*DV + t] + Wpos[(long)p*DM + d];
        xf[(long)bp*DM + d] = v;
        xb[(long)bp*DM + d] = (bf16_t)v;
    }
}

// qkv_flat [b,p,3072] -> q[b,h,p,dh], k[b,h,p,dh], vT[b,h,dh,p]
__global__ __launch_bounds__(256) void k_permute_qkv(const bf16_t* __restrict__ qkv,
    bf16_t* __restrict__ q, bf16_t* __restrict__ k, bf16_t* __restrict__ vt)
{
    long idx = (long)blockIdx.x*256 + threadIdx.x;    // MTOK*3072
    int n = (int)(idx % 3072);
    long bp = idx / 3072;
    int b = (int)(bp >> 11), p = (int)(bp & 2047);
    int sel = n >> 10, m = n & 1023;
    int i = m >> 6, hh = m & 63;
    bf16_t v = qkv[idx];
    long bh = (long)b*NH + i;
    if (sel == 0)      q[(bh*S + p)*DH + hh] = v;
    else if (sel == 1) k[(bh*S + p)*DH + hh] = v;
    else               vt[(bh*DH + hh)*S + p] = v;
}

// Masked, scaled, in-place softmax over key dim. One wave per query row.
__global__ __launch_bounds__(256) void k_softmax(bf16_t* __restrict__ scores)
{
    int rid  = blockIdx.x*4 + (threadIdx.x >> 6);
    int lane = threadIdx.x & 63;
    int z = rid >> 11, q = rid & 2047;
    bf16_t* row = scores + ((long)z*S + q)*S;
    const float scale = 0.125f;   // 1/sqrt(64)
    float vals[32];
    int k0 = lane*32;
    float m = -1e30f;
#pragma unroll
    for (int u=0;u<4;u++) {
        bf16x8 v8 = *(const bf16x8*)&row[k0 + u*8];
#pragma unroll
        for (int j=0;j<8;j++) {
            int k = k0 + u*8 + j;
            float s = (k <= q) ? (float)v8[j]*scale : -1e30f;
            vals[u*8+j] = s;
            m = fmaxf(m, s);
        }
    }
#pragma unroll
    for (int off=32; off; off>>=1) m = fmaxf(m, __shfl_xor(m, off));
    float sum = 0.f;
#pragma unroll
    for (int t=0;t<32;t++) { float e = __expf(vals[t]-m); vals[t]=e; sum += e; }
#pragma unroll
    for (int off=32; off; off>>=1) sum += __shfl_xor(sum, off);
    float rs = 1.0f/sum;
#pragma unroll
    for (int u=0;u<4;u++) {
        bf16x8 o;
#pragma unroll
        for (int j=0;j<8;j++) o[j] = (bf16_t)(vals[u*8+j]*rs);
        *(bf16x8*)&row[k0+u*8] = o;
    }
}

// ---------------------------------------------------------------------------
extern "C" void kernel_launch(void* const* d_in, const int* in_sizes, int n_in,
                              void* d_out, int out_size, void* d_ws, size_t ws_size,
                              hipStream_t stream)
{
    const int*   tokens = (const int*)d_in[0];
    const float* W_E    = (const float*)d_in[1];
    const float* W_pos  = (const float*)d_in[2];
    const float* W_K    = (const float*)d_in[3];
    const float* W_Q    = (const float*)d_in[4];
    const float* W_V    = (const float*)d_in[5];
    const float* W_O    = (const float*)d_in[6];
    const float* W_in   = (const float*)d_in[7];
    const float* b_in   = (const float*)d_in[8];
    const float* W_out  = (const float*)d_in[9];
    const float* b_out  = (const float*)d_in[10];
    const float* W_U    = (const float*)d_in[11];
    float* out = (float*)d_out;

    char* ws = (char*)d_ws;
    long off = 0;
    auto alloc = [&](long bytes)->char* {
        char* p = ws + off; off += (bytes + 255) & ~255L; return p;
    };
    bf16_t* wqkv = (bf16_t*)alloc((long)NL*3072*DM*2);
    bf16_t* wo   = (bf16_t*)alloc((long)NL*DM*DM*2);
    bf16_t* win  = (bf16_t*)alloc((long)NL*DMLP*DM*2);
    bf16_t* wout = (bf16_t*)alloc((long)NL*DM*DMLP*2);
    bf16_t* wut  = (bf16_t*)alloc((long)DV*DM*2);
    float*  xf   = (float*)alloc((long)MTOK*DM*4);
    bf16_t* xb   = (bf16_t*)alloc((long)MTOK*DM*2);
    bf16_t* qkvf = (bf16_t*)alloc((long)MTOK*3072*2);
    bf16_t* qb   = (bf16_t*)alloc((long)BATCH*NH*S*DH*2);
    bf16_t* kb   = (bf16_t*)alloc((long)BATCH*NH*S*DH*2);
    bf16_t* vt   = (bf16_t*)alloc((long)BATCH*NH*S*DH*2);
    bf16_t* zf   = (bf16_t*)alloc((long)MTOK*DM*2);
    bf16_t* post = (bf16_t*)alloc((long)MTOK*DMLP*2);
    bf16_t* sc   = (bf16_t*)alloc((long)CH*S*S*2);

    // --- weight conversion (per launch; deterministic) ---
    k_conv_qkv<<<(int)(((long)NL*3072*DM)/256), 256, 0, stream>>>(W_Q, W_K, W_V, wqkv);
    k_conv<<<(int)(((long)NL*DM*DM)/1024),   256, 0, stream>>>(W_O,   wo,   (long)NL*DM*DM);
    k_conv<<<(int)(((long)NL*DMLP*DM)/1024), 256, 0, stream>>>(W_in,  win,  (long)NL*DMLP*DM);
    k_conv<<<(int)(((long)NL*DM*DMLP)/1024), 256, 0, stream>>>(W_out, wout, (long)NL*DM*DMLP);
    k_trans_wu<<<dim3(DV/32, DM/32), 256, 0, stream>>>(W_U, wut);

    // --- embed ---
    k_embed<<<MTOK, 256, 0, stream>>>(tokens, W_E, W_pos, xf, xb);

    for (int l = 0; l < NL; ++l) {
        // QKV (fused N=3072)
        gemm_tn<128,128,0,false,false,0><<<dim3(MTOK/128, 3072/128, 1), 256, 0, stream>>>(
            xb, 0L, wqkv + (long)l*3072*DM, 0L, (char*)qkvf, 0L, 3072,
            nullptr, nullptr, nullptr, DM);
        k_permute_qkv<<<(int)(((long)MTOK*3072)/256), 256, 0, stream>>>(qkvf, qb, kb, vt);

        for (int c = 0; c < (BATCH*NH)/CH; ++c) {
            int bh0 = c*CH;
            int b   = bh0 >> 4;
            int i0  = bh0 & 15;
            // scores[z][q][p] = Q[q,:]·K[p,:]
            gemm_tn<128,128,0,false,false,1><<<dim3(S/128, S/128, CH), 256, 0, stream>>>(
                qb + (long)bh0*S*DH, (long)S*DH,
                kb + (long)bh0*S*DH, (long)S*DH,
                (char*)sc, (long)S*S, S, nullptr, nullptr, nullptr, DH);
            k_softmax<<<(CH*S)/4, 256, 0, stream>>>(sc);
            // z[q][hh] = P[q,:]·V[:,hh], written straight into z_flat [b,q,(i,hh)]
            gemm_tn<128,64,0,false,false,2><<<dim3(S/128, 1, CH), 256, 0, stream>>>(
                sc, (long)S*S,
                vt + (long)bh0*DH*S, (long)DH*S,
                (char*)(zf + (long)b*S*DM + (long)i0*DH), 64L, DM,
                nullptr, nullptr, nullptr, S);
        }

        // attn_out = z_flat @ W_O^T, fused residual add into x
        gemm_tn<128,128,2,false,false,0><<<dim3(MTOK/128, DM/128, 1), 256, 0, stream>>>(
            zf, 0L, wo + (long)l*DM*DM, 0L, nullptr, 0L, DM,
            nullptr, xf, xb, DM);
        // MLP in: relu(x @ W_in^T + b_in)
        gemm_tn<128,128,0,true,true,0><<<dim3(MTOK/128, DMLP/128, 1), 256, 0, stream>>>(
            xb, 0L, win + (long)l*DMLP*DM, 0L, (char*)post, 0L, DMLP,
            b_in + (long)l*DMLP, nullptr, nullptr, DM);
        // MLP out + b_out, fused residual add into x
        gemm_tn<128,128,2,true,false,0><<<dim3(MTOK/128, DM/128, 1), 256, 0, stream>>>(
            post, 0L, wout + (long)l*DM*DMLP, 0L, nullptr, 0L, DM,
            b_out + (long)l*DM, xf, xb, DMLP);
    }

    // logits = x @ W_U  (f32 out)
    gemm_tn<128,128,1,false,false,0><<<dim3(MTOK/128, DV/128, 1), 256, 0, stream>>>(
        xb, 0L, wut, 0L, (char*)out, 0L, DV,
        nullptr, nullptr, nullptr, DM);
}

// Round 3
// 2776.112 us; speedup vs baseline: 1.4136x; 1.4136x over previous
//
#include <hip/hip_runtime.h>
#include <hip/hip_bf16.h>
#include <math.h>

// Model dims
#define DV   32000
#define DM   1024
#define DMLP 4096
#define DH   64
#define NH   16
#define NL   4
#define BATCH 2
#define S    2048
#define MTOK (BATCH*S)   // 4096 tokens
#define CH   8           // heads per attention chunk

typedef __bf16 bf16_t;
typedef bf16_t bf16x8 __attribute__((ext_vector_type(8)));
typedef float  f32x4  __attribute__((ext_vector_type(4)));

#define AS1 __attribute__((address_space(1)))
#define AS3 __attribute__((address_space(3)))

__device__ __forceinline__ void gload16(const bf16_t* g, bf16_t* l) {
    __builtin_amdgcn_global_load_lds((const AS1 void*)g, (AS3 void*)l, 16, 0, 0);
}

// ---------------------------------------------------------------------------
// Generic TN GEMM: C[M,N] = A[M,K] * B[N,K]^T, bf16 in, f32 accum.
// Grid: (M/BM, N/BN, Z)  -- M on x so consecutive blocks share the B panel.
// LDS: row-major [R][BK=64] bf16 (128B rows), 16B-chunk XOR swizzle
//   physical_chunk = logical_chunk ^ (row & 7)
// applied BOTH on the global source address (stage) and the ds_read (rule:
// linear dest + inverse-swz source + swz read). Coalesced staging AND
// conflict-free fragment reads.
// MODE 0: write bf16 (optional bias/relu)
// MODE 1: write f32  (optional bias)
// MODE 2: residual add: resid_f32 += acc(+bias); residb_bf16 = bf16(resid)
// CAUSAL 0: none; 1: skip fully-masked key tiles (scores GEMM);
//        2: truncate K-loop at causal boundary (PV GEMM)
// Requirements: M%BM==0, N%BN==0, K%64==0.
// ---------------------------------------------------------------------------
template<int BM, int BN, int MODE, bool BIAS, bool RELU, int CAUSAL>
__global__ __launch_bounds__(256)
void gemm_tn(const bf16_t* __restrict__ A, long sA,
             const bf16_t* __restrict__ Bm, long sB,
             char* __restrict__ Out, long sC, int ldc,
             const float* __restrict__ bias,
             float* __restrict__ resid, bf16_t* __restrict__ residb,
             int K)
{
    constexpr int BK = 64;
    constexpr int WM = BM/2, WN = BN/2;
    constexpr int FM = WM/16, FN = WN/16;
    constexpr int APASS = (BM*BK)/(256*8);   // 16B chunks per thread for A
    constexpr int BPASS = (BN*BK)/(256*8);

    const int mb = blockIdx.x, nb = blockIdx.y;
    if (CAUSAL == 1 && nb*BN >= mb*BM + BM) return;   // fully-masked tile

    __shared__ alignas(16) bf16_t As[BM*BK];
    __shared__ alignas(16) bf16_t Bs[BN*BK];

    const int tid  = threadIdx.x;
    const int wave = tid >> 6, lane = tid & 63;
    const int wm = wave >> 1, wn = wave & 1;
    const int l16 = lane & 15, lh = lane >> 4;
    const long z = blockIdx.z;

    const bf16_t* Ab = A  + z*sA + (long)mb*BM*K;
    const bf16_t* Bb = Bm + z*sB + (long)nb*BN*K;

    f32x4 acc[FM][FN];
#pragma unroll
    for (int i=0;i<FM;i++)
#pragma unroll
        for (int j=0;j<FN;j++) { f32x4 zv = {0.f,0.f,0.f,0.f}; acc[i][j] = zv; }

    int Kend = (CAUSAL == 2) ? ((mb+1)*BM < K ? (mb+1)*BM : K) : K;

    for (int k0 = 0; k0 < Kend; k0 += BK) {
        __syncthreads();   // all waves done reading previous tile
        // stage: physical chunk c -> LDS byte c*16 (linear in tid);
        // source = logical chunk (c&7)^(row&7) of row c>>3  (coalesced:
        // 8 lanes cover one 128B row, permuted within the row)
#pragma unroll
        for (int u=0; u<APASS; ++u) {
            int c = u*256 + tid;
            int row = c >> 3, lc = (c & 7) ^ (row & 7);
            gload16(&Ab[(long)row*K + k0 + lc*8], &As[c*8]);
        }
#pragma unroll
        for (int u=0; u<BPASS; ++u) {
            int c = u*256 + tid;
            int row = c >> 3, lc = (c & 7) ^ (row & 7);
            gload16(&Bb[(long)row*K + k0 + lc*8], &Bs[c*8]);
        }
        __syncthreads();   // vmcnt(0) drain + barrier

        bf16x8 af[FM][2], bfr[FN][2];
#pragma unroll
        for (int kk=0;kk<2;kk++) {
#pragma unroll
            for (int i=0;i<FM;i++) {
                int row = wm*WM + i*16 + l16;
                int pw = (kk*4 + lh) ^ (row & 7);
                af[i][kk] = *(const bf16x8*)&As[row*BK + pw*8];
            }
#pragma unroll
            for (int j=0;j<FN;j++) {
                int row = wn*WN + j*16 + l16;
                int pw = (kk*4 + lh) ^ (row & 7);
                bfr[j][kk] = *(const bf16x8*)&Bs[row*BK + pw*8];
            }
        }
#pragma unroll
        for (int kk=0;kk<2;kk++)
#pragma unroll
            for (int i=0;i<FM;i++)
#pragma unroll
                for (int j=0;j<FN;j++)
                    acc[i][j] = __builtin_amdgcn_mfma_f32_16x16x32_bf16(af[i][kk], bfr[j][kk], acc[i][j], 0,0,0);
    }

    // epilogue: C/D layout col=lane&15, row=(lane>>4)*4+reg  [measured m89/m91]
#pragma unroll
    for (int i=0;i<FM;i++) {
        int row0 = mb*BM + wm*WM + i*16 + lh*4;
#pragma unroll
        for (int j=0;j<FN;j++) {
            int col = nb*BN + wn*WN + j*16 + l16;
            float bv = BIAS ? bias[col] : 0.0f;
#pragma unroll
            for (int r=0;r<4;r++) {
                int row = row0 + r;
                float v = acc[i][j][r] + bv;
                if (RELU) v = v > 0.f ? v : 0.f;
                if constexpr (MODE == 0) {
                    long off = z*sC + (long)row*ldc + col;
                    ((bf16_t*)Out)[off] = (bf16_t)v;
                } else if constexpr (MODE == 1) {
                    long off = z*sC + (long)row*ldc + col;
                    ((float*)Out)[off] = v;
                } else {
                    long o2 = (long)row*ldc + col;
                    float nv = resid[o2] + v;
                    resid[o2]  = nv;
                    residb[o2] = (bf16_t)nv;
                }
            }
        }
    }
}

// ---------------------------------------------------------------------------
// Weight conversion kernels
// ---------------------------------------------------------------------------
__global__ __launch_bounds__(256) void k_conv_qkv(
    const float* __restrict__ Wq, const float* __restrict__ Wk,
    const float* __restrict__ Wv, bf16_t* __restrict__ out)
{
    long idx = (long)blockIdx.x*256 + threadIdx.x;   // NL*3072*DM total
    long l = idx / (3072L*DM);
    long r = idx % (3072L*DM);
    int row = (int)(r / DM), d = (int)(r % DM);
    int sel = row >> 10, rr = row & 1023;
    const float* src = sel==0 ? Wq : (sel==1 ? Wk : Wv);
    out[idx] = (bf16_t)src[(l*1024 + rr)*(long)DM + d];
}

__global__ __launch_bounds__(256) void k_conv(const float* __restrict__ src,
                                              bf16_t* __restrict__ dst, long n)
{
    long i = ((long)blockIdx.x*256 + threadIdx.x)*4;
    if (i >= n) return;
    float4 v = *(const float4*)&src[i];
    dst[i+0]=(bf16_t)v.x; dst[i+1]=(bf16_t)v.y; dst[i+2]=(bf16_t)v.z; dst[i+3]=(bf16_t)v.w;
}

// W_U [DM][DV] -> WUt [DV][DM] bf16 (tiled transpose)
__global__ __launch_bounds__(256) void k_trans_wu(const float* __restrict__ W,
                                                  bf16_t* __restrict__ out)
{
    __shared__ float tile[32][33];
    int n0 = blockIdx.x*32, k0 = blockIdx.y*32;
    int tx = threadIdx.x & 31, ty = threadIdx.x >> 5;   // ty 0..7
#pragma unroll
    for (int u=0;u<4;u++)
        tile[ty+u*8][tx] = W[(long)(k0+ty+u*8)*DV + n0+tx];
    __syncthreads();
#pragma unroll
    for (int u=0;u<4;u++)
        out[(long)(n0+ty+u*8)*DM + k0+tx] = (bf16_t)tile[tx][ty+u*8];
}

// ---------------------------------------------------------------------------
// Embedding: x[b,p,d] = W_E[d, tok[b,p]] + W_pos[p,d]
// ---------------------------------------------------------------------------
__global__ __launch_bounds__(256) void k_embed(const int* __restrict__ tok,
    const float* __restrict__ WE, const float* __restrict__ Wpos,
    float* __restrict__ xf, bf16_t* __restrict__ xb)
{
    int bp = blockIdx.x;
    int p  = bp & (S-1);
    int t  = tok[bp];
#pragma unroll
    for (int u=0;u<4;u++) {
        int d = u*256 + threadIdx.x;
        float v = WE[(long)d*DV + t] + Wpos[(long)p*DM + d];
        xf[(long)bp*DM + d] = v;
        xb[(long)bp*DM + d] = (bf16_t)v;
    }
}

// qkv_flat [b,p,3072] -> q[b,h,p,dh], k[b,h,p,dh], vT[b,h,dh,p]
__global__ __launch_bounds__(256) void k_permute_qkv(const bf16_t* __restrict__ qkv,
    bf16_t* __restrict__ q, bf16_t* __restrict__ k, bf16_t* __restrict__ vt)
{
    long idx = (long)blockIdx.x*256 + threadIdx.x;    // MTOK*3072
    int n = (int)(idx % 3072);
    long bp = idx / 3072;
    int b = (int)(bp >> 11), p = (int)(bp & 2047);
    int sel = n >> 10, m = n & 1023;
    int i = m >> 6, hh = m & 63;
    bf16_t v = qkv[idx];
    long bh = (long)b*NH + i;
    if (sel == 0)      q[(bh*S + p)*DH + hh] = v;
    else if (sel == 1) k[(bh*S + p)*DH + hh] = v;
    else               vt[(bh*DH + hh)*S + p] = v;
}

// Masked, scaled, in-place softmax over key dim. One wave per query row.
__global__ __launch_bounds__(256) void k_softmax(bf16_t* __restrict__ scores)
{
    int rid  = blockIdx.x*4 + (threadIdx.x >> 6);
    int lane = threadIdx.x & 63;
    int z = rid >> 11, q = rid & 2047;
    bf16_t* row = scores + ((long)z*S + q)*S;
    const float scale = 0.125f;   // 1/sqrt(64)
    float vals[32];
    int k0 = lane*32;
    float m = -1e30f;
#pragma unroll
    for (int u=0;u<4;u++) {
        bf16x8 v8 = *(const bf16x8*)&row[k0 + u*8];
#pragma unroll
        for (int j=0;j<8;j++) {
            int k = k0 + u*8 + j;
            float s = (k <= q) ? (float)v8[j]*scale : -1e30f;
            vals[u*8+j] = s;
            m = fmaxf(m, s);
        }
    }
#pragma unroll
    for (int off=32; off; off>>=1) m = fmaxf(m, __shfl_xor(m, off));
    float sum = 0.f;
#pragma unroll
    for (int t=0;t<32;t++) { float e = __expf(vals[t]-m); vals[t]=e; sum += e; }
#pragma unroll
    for (int off=32; off; off>>=1) sum += __shfl_xor(sum, off);
    float rs = 1.0f/sum;
#pragma unroll
    for (int u=0;u<4;u++) {
        bf16x8 o;
#pragma unroll
        for (int j=0;j<8;j++) o[j] = (bf16_t)(vals[u*8+j]*rs);
        *(bf16x8*)&row[k0+u*8] = o;
    }
}

// ---------------------------------------------------------------------------
extern "C" void kernel_launch(void* const* d_in, const int* in_sizes, int n_in,
                              void* d_out, int out_size, void* d_ws, size_t ws_size,
                              hipStream_t stream)
{
    const int*   tokens = (const int*)d_in[0];
    const float* W_E    = (const float*)d_in[1];
    const float* W_pos  = (const float*)d_in[2];
    const float* W_K    = (const float*)d_in[3];
    const float* W_Q    = (const float*)d_in[4];
    const float* W_V    = (const float*)d_in[5];
    const float* W_O    = (const float*)d_in[6];
    const float* W_in   = (const float*)d_in[7];
    const float* b_in   = (const float*)d_in[8];
    const float* W_out  = (const float*)d_in[9];
    const float* b_out  = (const float*)d_in[10];
    const float* W_U    = (const float*)d_in[11];
    float* out = (float*)d_out;

    char* ws = (char*)d_ws;
    long off = 0;
    auto alloc = [&](long bytes)->char* {
        char* p = ws + off; off += (bytes + 255) & ~255L; return p;
    };
    bf16_t* wqkv = (bf16_t*)alloc((long)NL*3072*DM*2);
    bf16_t* wo   = (bf16_t*)alloc((long)NL*DM*DM*2);
    bf16_t* win  = (bf16_t*)alloc((long)NL*DMLP*DM*2);
    bf16_t* wout = (bf16_t*)alloc((long)NL*DM*DMLP*2);
    bf16_t* wut  = (bf16_t*)alloc((long)DV*DM*2);
    float*  xf   = (float*)alloc((long)MTOK*DM*4);
    bf16_t* xb   = (bf16_t*)alloc((long)MTOK*DM*2);
    bf16_t* qkvf = (bf16_t*)alloc((long)MTOK*3072*2);
    bf16_t* qb   = (bf16_t*)alloc((long)BATCH*NH*S*DH*2);
    bf16_t* kb   = (bf16_t*)alloc((long)BATCH*NH*S*DH*2);
    bf16_t* vt   = (bf16_t*)alloc((long)BATCH*NH*S*DH*2);
    bf16_t* zf   = (bf16_t*)alloc((long)MTOK*DM*2);
    bf16_t* post = (bf16_t*)alloc((long)MTOK*DMLP*2);
    bf16_t* sc   = (bf16_t*)alloc((long)CH*S*S*2);

    // --- weight conversion (per launch; deterministic) ---
    k_conv_qkv<<<(int)(((long)NL*3072*DM)/256), 256, 0, stream>>>(W_Q, W_K, W_V, wqkv);
    k_conv<<<(int)(((long)NL*DM*DM)/1024),   256, 0, stream>>>(W_O,   wo,   (long)NL*DM*DM);
    k_conv<<<(int)(((long)NL*DMLP*DM)/1024), 256, 0, stream>>>(W_in,  win,  (long)NL*DMLP*DM);
    k_conv<<<(int)(((long)NL*DM*DMLP)/1024), 256, 0, stream>>>(W_out, wout, (long)NL*DM*DMLP);
    k_trans_wu<<<dim3(DV/32, DM/32), 256, 0, stream>>>(W_U, wut);

    // --- embed ---
    k_embed<<<MTOK, 256, 0, stream>>>(tokens, W_E, W_pos, xf, xb);

    for (int l = 0; l < NL; ++l) {
        // QKV (fused N=3072)
        gemm_tn<128,128,0,false,false,0><<<dim3(MTOK/128, 3072/128, 1), 256, 0, stream>>>(
            xb, 0L, wqkv + (long)l*3072*DM, 0L, (char*)qkvf, 0L, 3072,
            nullptr, nullptr, nullptr, DM);
        k_permute_qkv<<<(int)(((long)MTOK*3072)/256), 256, 0, stream>>>(qkvf, qb, kb, vt);

        for (int c = 0; c < (BATCH*NH)/CH; ++c) {
            int bh0 = c*CH;
            int b   = bh0 >> 4;
            int i0  = bh0 & 15;
            // scores[z][q][p] = Q[q,:]·K[p,:]
            gemm_tn<128,128,0,false,false,1><<<dim3(S/128, S/128, CH), 256, 0, stream>>>(
                qb + (long)bh0*S*DH, (long)S*DH,
                kb + (long)bh0*S*DH, (long)S*DH,
                (char*)sc, (long)S*S, S, nullptr, nullptr, nullptr, DH);
            k_softmax<<<(CH*S)/4, 256, 0, stream>>>(sc);
            // z[q][hh] = P[q,:]·V[:,hh], written straight into z_flat [b,q,(i,hh)]
            gemm_tn<128,64,0,false,false,2><<<dim3(S/128, 1, CH), 256, 0, stream>>>(
                sc, (long)S*S,
                vt + (long)bh0*DH*S, (long)DH*S,
                (char*)(zf + (long)b*S*DM + (long)i0*DH), 64L, DM,
                nullptr, nullptr, nullptr, S);
        }

        // attn_out = z_flat @ W_O^T, fused residual add into x
        gemm_tn<128,128,2,false,false,0><<<dim3(MTOK/128, DM/128, 1), 256, 0, stream>>>(
            zf, 0L, wo + (long)l*DM*DM, 0L, nullptr, 0L, DM,
            nullptr, xf, xb, DM);
        // MLP in: relu(x @ W_in^T + b_in)
        gemm_tn<128,128,0,true,true,0><<<dim3(MTOK/128, DMLP/128, 1), 256, 0, stream>>>(
            xb, 0L, win + (long)l*DMLP*DM, 0L, (char*)post, 0L, DMLP,
            b_in + (long)l*DMLP, nullptr, nullptr, DM);
        // MLP out + b_out, fused residual add into x
        gemm_tn<128,128,2,true,false,0><<<dim3(MTOK/128, DM/128, 1), 256, 0, stream>>>(
            post, 0L, wout + (long)l*DM*DMLP, 0L, nullptr, 0L, DM,
            b_out + (long)l*DM, xf, xb, DMLP);
    }

    // logits = x @ W_U  (f32 out)
    gemm_tn<128,128,1,false,false,0><<<dim3(MTOK/128, DV/128, 1), 256, 0, stream>>>(
        xb, 0L, wut, 0L, (char*)out, 0L, DV,
        nullptr, nullptr, nullptr, DM);
}

// Round 4
// 1917.828 us; speedup vs baseline: 2.0463x; 1.4475x over previous
//
#include <hip/hip_runtime.h>
#include <hip/hip_bf16.h>
#include <math.h>

// Model dims
#define DV   32000
#define DM   1024
#define DMLP 4096
#define DH   64
#define NH   16
#define NL   4
#define BATCH 2
#define S    2048
#define MTOK (BATCH*S)   // 4096 tokens

typedef __bf16 bf16_t;
typedef bf16_t bf16x8 __attribute__((ext_vector_type(8)));
typedef float  f32x4  __attribute__((ext_vector_type(4)));

#define AS1 __attribute__((address_space(1)))
#define AS3 __attribute__((address_space(3)))

__device__ __forceinline__ void gload16(const bf16_t* g, bf16_t* l) {
    __builtin_amdgcn_global_load_lds((const AS1 void*)g, (AS3 void*)l, 16, 0, 0);
}

__device__ __forceinline__ unsigned short bfbits(float v) {
    union { bf16_t b; unsigned short u; } c; c.b = (bf16_t)v; return c.u;
}

// ---------------------------------------------------------------------------
// Generic TN GEMM: C[M,N] = A[M,K] * B[N,K]^T, bf16 in, f32 accum.
// Grid: (M/BM, N/BN, Z).  LDS: row-major [R][BK=64] (128B rows), 16B-chunk
// XOR swizzle phys = logical ^ (row&7), applied on stage-source and ds_read.
// MODE 0: write bf16 (optional bias/relu); MODE 1: write f32;
// MODE 2: resid_f32 += acc(+bias); residb_bf16 = bf16(resid)
// ---------------------------------------------------------------------------
template<int BM, int BN, int MODE, bool BIAS, bool RELU>
__global__ __launch_bounds__(256)
void gemm_tn(const bf16_t* __restrict__ A, long sA,
             const bf16_t* __restrict__ Bm, long sB,
             char* __restrict__ Out, long sC, int ldc,
             const float* __restrict__ bias,
             float* __restrict__ resid, bf16_t* __restrict__ residb,
             int K)
{
    constexpr int BK = 64;
    constexpr int WM = BM/2, WN = BN/2;
    constexpr int FM = WM/16, FN = WN/16;
    constexpr int APASS = (BM*BK)/(256*8);
    constexpr int BPASS = (BN*BK)/(256*8);

    const int mb = blockIdx.x, nb = blockIdx.y;

    __shared__ alignas(16) bf16_t As[BM*BK];
    __shared__ alignas(16) bf16_t Bs[BN*BK];

    const int tid  = threadIdx.x;
    const int wave = tid >> 6, lane = tid & 63;
    const int wm = wave >> 1, wn = wave & 1;
    const int l16 = lane & 15, lh = lane >> 4;
    const long z = blockIdx.z;

    const bf16_t* Ab = A  + z*sA + (long)mb*BM*K;
    const bf16_t* Bb = Bm + z*sB + (long)nb*BN*K;

    f32x4 acc[FM][FN];
#pragma unroll
    for (int i=0;i<FM;i++)
#pragma unroll
        for (int j=0;j<FN;j++) { f32x4 zv = {0.f,0.f,0.f,0.f}; acc[i][j] = zv; }

    for (int k0 = 0; k0 < K; k0 += BK) {
        __syncthreads();
#pragma unroll
        for (int u=0; u<APASS; ++u) {
            int c = u*256 + tid;
            int row = c >> 3, lc = (c & 7) ^ (row & 7);
            gload16(&Ab[(long)row*K + k0 + lc*8], &As[c*8]);
        }
#pragma unroll
        for (int u=0; u<BPASS; ++u) {
            int c = u*256 + tid;
            int row = c >> 3, lc = (c & 7) ^ (row & 7);
            gload16(&Bb[(long)row*K + k0 + lc*8], &Bs[c*8]);
        }
        __syncthreads();

        bf16x8 af[FM][2], bfr[FN][2];
#pragma unroll
        for (int kk=0;kk<2;kk++) {
#pragma unroll
            for (int i=0;i<FM;i++) {
                int row = wm*WM + i*16 + l16;
                int pw = (kk*4 + lh) ^ (row & 7);
                af[i][kk] = *(const bf16x8*)&As[row*BK + pw*8];
            }
#pragma unroll
            for (int j=0;j<FN;j++) {
                int row = wn*WN + j*16 + l16;
                int pw = (kk*4 + lh) ^ (row & 7);
                bfr[j][kk] = *(const bf16x8*)&Bs[row*BK + pw*8];
            }
        }
#pragma unroll
        for (int kk=0;kk<2;kk++)
#pragma unroll
            for (int i=0;i<FM;i++)
#pragma unroll
                for (int j=0;j<FN;j++)
                    acc[i][j] = __builtin_amdgcn_mfma_f32_16x16x32_bf16(af[i][kk], bfr[j][kk], acc[i][j], 0,0,0);
    }

#pragma unroll
    for (int i=0;i<FM;i++) {
        int row0 = mb*BM + wm*WM + i*16 + lh*4;
#pragma unroll
        for (int j=0;j<FN;j++) {
            int col = nb*BN + wn*WN + j*16 + l16;
            float bv = BIAS ? bias[col] : 0.0f;
#pragma unroll
            for (int r=0;r<4;r++) {
                int row = row0 + r;
                float v = acc[i][j][r] + bv;
                if (RELU) v = v > 0.f ? v : 0.f;
                if constexpr (MODE == 0) {
                    long off = z*sC + (long)row*ldc + col;
                    ((bf16_t*)Out)[off] = (bf16_t)v;
                } else if constexpr (MODE == 1) {
                    long off = z*sC + (long)row*ldc + col;
                    ((float*)Out)[off] = v;
                } else {
                    long o2 = (long)row*ldc + col;
                    float nv = resid[o2] + v;
                    resid[o2]  = nv;
                    residb[o2] = (bf16_t)nv;
                }
            }
        }
    }
}

// ---------------------------------------------------------------------------
// Flash attention (causal). Grid: (S/128, BATCH*NH). 4 waves; each wave owns
// 32 q-rows. KV tiles of 64 keys staged in LDS (K row-major, V^T row-major,
// both chunk-XOR swizzled). Swapped QK^T: mfma(K,Q) -> S^T[key][q]; softmax
// per q-column via 4-lane shfl group; P -> per-wave swizzled LDS; PV:
// mfma(V^T, P) -> O^T[dh][q]. Output written to z_flat [b,q,(head,dh)].
// ---------------------------------------------------------------------------
__global__ __launch_bounds__(256)
void flash_attn(const bf16_t* __restrict__ qkvf,  // [B][S][3072], Q at head*64
                const bf16_t* __restrict__ kg,    // [BH][S][DH]
                const bf16_t* __restrict__ vtg,   // [BH][DH][S]
                bf16_t* __restrict__ zf)          // [B][S][DM]
{
    const int qt = blockIdx.x;           // q-tile (128 rows)
    const int bh = blockIdx.y;           // 0..31
    const int b  = bh >> 4, hd = bh & 15;

    __shared__ alignas(16) bf16_t Kl[64*64];
    __shared__ alignas(16) bf16_t Vtl[64*64];
    __shared__ alignas(16) bf16_t Pl[4*32*64];

    const int tid = threadIdx.x;
    const int wave = tid >> 6, lane = tid & 63;
    const int l16 = lane & 15, lh = lane >> 4;
    const int wq_lo = qt*128 + wave*32;          // this wave's first q row
    bf16_t* Pw = Pl + wave*32*64;

    // Q fragments: [qf][dh-half], B-operand layout (lane: col q=l16, k=lh*8..)
    bf16x8 qr[2][2];
#pragma unroll
    for (int qf=0; qf<2; qf++) {
        int qg = wq_lo + qf*16 + l16;
#pragma unroll
        for (int dhh=0; dhh<2; dhh++)
            qr[qf][dhh] = *(const bf16x8*)&qkvf[((long)b*S + qg)*3072 + hd*64 + dhh*32 + lh*8];
    }

    f32x4 o[4][2];                                // O^T acc [dh-frag][qf]
#pragma unroll
    for (int d=0; d<4; d++)
#pragma unroll
        for (int qf=0; qf<2; qf++) { f32x4 zv={0.f,0.f,0.f,0.f}; o[d][qf]=zv; }
    float mrun[2] = {-1e30f, -1e30f};
    float lrun[2] = {0.f, 0.f};

    const int nt = 2*(qt+1);                      // 64-key tiles needed
    const float C = 0.125f;                       // 1/sqrt(DH)

    for (int t = 0; t < nt; ++t) {
        const int kv0 = t*64;
        __syncthreads();
        // stage K tile [64 key][64 dh] and V^T tile [64 dh][64 key]
#pragma unroll
        for (int u=0; u<2; ++u) {
            int c = u*256 + tid;
            int row = c >> 3, lc = (c & 7) ^ (row & 7);
            gload16(&kg[((long)bh*S + kv0 + row)*DH + lc*8], &Kl[c*8]);
        }
#pragma unroll
        for (int u=0; u<2; ++u) {
            int c = u*256 + tid;
            int row = c >> 3, lc = (c & 7) ^ (row & 7);
            gload16(&vtg[((long)bh*DH + row)*S + kv0 + lc*8], &Vtl[c*8]);
        }
        __syncthreads();

        // ---- QK^T (swapped): s[f][qf] = S^T tile [key 16f..][q 16qf..]
        f32x4 s[4][2];
#pragma unroll
        for (int f=0; f<4; f++)
#pragma unroll
            for (int qf=0; qf<2; qf++) { f32x4 zv={0.f,0.f,0.f,0.f}; s[f][qf]=zv; }
#pragma unroll
        for (int f=0; f<4; f++) {
            int krow = f*16 + l16;
#pragma unroll
            for (int dhh=0; dhh<2; dhh++) {
                bf16x8 kfr = *(const bf16x8*)&Kl[krow*64 + (((dhh*4+lh) ^ (krow&7))*8)];
#pragma unroll
                for (int qf=0; qf<2; qf++)
                    s[f][qf] = __builtin_amdgcn_mfma_f32_16x16x32_bf16(kfr, qr[qf][dhh], s[f][qf], 0,0,0);
            }
        }

        const bool needmask = (kv0 + 64 > wq_lo);

        // ---- online softmax per qf (q = wq_lo + qf*16 + l16)
#pragma unroll
        for (int qf=0; qf<2; qf++) {
            int qg = wq_lo + qf*16 + l16;
            float pmax = -1e30f;
#pragma unroll
            for (int f=0; f<4; f++)
#pragma unroll
                for (int r=0; r<4; r++) {
                    float sv = s[f][qf][r];
                    if (needmask && (kv0 + f*16 + lh*4 + r > qg)) { sv = -1e30f; s[f][qf][r] = sv; }
                    pmax = fmaxf(pmax, sv);
                }
            pmax = fmaxf(pmax, __shfl_xor(pmax, 16));
            pmax = fmaxf(pmax, __shfl_xor(pmax, 32));
            float mnew = fmaxf(mrun[qf], pmax);
            float corr = __expf((mrun[qf] - mnew)*C);
            mrun[qf] = mnew;
            lrun[qf] *= corr;
#pragma unroll
            for (int d=0; d<4; d++) o[d][qf] *= corr;
            float lsum = 0.f;
            int qloc = qf*16 + l16;
#pragma unroll
            for (int f=0; f<4; f++) {
                ushort4 pk;
                float p0 = __expf((s[f][qf][0]-mnew)*C);
                float p1 = __expf((s[f][qf][1]-mnew)*C);
                float p2 = __expf((s[f][qf][2]-mnew)*C);
                float p3 = __expf((s[f][qf][3]-mnew)*C);
                lsum += (p0+p1) + (p2+p3);
                pk.x = bfbits(p0); pk.y = bfbits(p1); pk.z = bfbits(p2); pk.w = bfbits(p3);
                int phys = (f*2 + (lh>>1)) ^ (qloc & 7);
                *(ushort4*)&Pw[qloc*64 + phys*8 + (lh&1)*4] = pk;
            }
            lrun[qf] += lsum;
        }

        // ---- PV: o[d][qf] += V^T[dh][keys] * P^T[keys][q]
#pragma unroll
        for (int kh=0; kh<2; kh++) {
            bf16x8 pb[2];
#pragma unroll
            for (int qf=0; qf<2; qf++) {
                int qloc = qf*16 + l16;
                pb[qf] = *(const bf16x8*)&Pw[qloc*64 + (((kh*4+lh) ^ (qloc&7))*8)];
            }
#pragma unroll
            for (int d=0; d<4; d++) {
                int vrow = d*16 + l16;
                bf16x8 va = *(const bf16x8*)&Vtl[vrow*64 + (((kh*4+lh) ^ (vrow&7))*8)];
#pragma unroll
                for (int qf=0; qf<2; qf++)
                    o[d][qf] = __builtin_amdgcn_mfma_f32_16x16x32_bf16(va, pb[qf], o[d][qf], 0,0,0);
            }
        }
    }

    // ---- epilogue: normalize and write z_flat[b][q][hd*64 + dh]
#pragma unroll
    for (int qf=0; qf<2; qf++) {
        float lt = lrun[qf];
        lt += __shfl_xor(lt, 16);
        lt += __shfl_xor(lt, 32);
        float inv = 1.0f / lt;
        int qg = wq_lo + qf*16 + l16;
#pragma unroll
        for (int d=0; d<4; d++) {
            ushort4 ov;
            ov.x = bfbits(o[d][qf][0]*inv);
            ov.y = bfbits(o[d][qf][1]*inv);
            ov.z = bfbits(o[d][qf][2]*inv);
            ov.w = bfbits(o[d][qf][3]*inv);
            *(ushort4*)&zf[((long)b*S + qg)*DM + hd*64 + d*16 + lh*4] = ov;
        }
    }
}

// ---------------------------------------------------------------------------
// Weight conversion kernels
// ---------------------------------------------------------------------------
__global__ __launch_bounds__(256) void k_conv_qkv(
    const float* __restrict__ Wq, const float* __restrict__ Wk,
    const float* __restrict__ Wv, bf16_t* __restrict__ out)
{
    long idx = (long)blockIdx.x*256 + threadIdx.x;   // NL*3072*DM total
    long l = idx / (3072L*DM);
    long r = idx % (3072L*DM);
    int row = (int)(r / DM), d = (int)(r % DM);
    int sel = row >> 10, rr = row & 1023;
    const float* src = sel==0 ? Wq : (sel==1 ? Wk : Wv);
    out[idx] = (bf16_t)src[(l*1024 + rr)*(long)DM + d];
}

__global__ __launch_bounds__(256) void k_conv(const float* __restrict__ src,
                                              bf16_t* __restrict__ dst, long n)
{
    long i = ((long)blockIdx.x*256 + threadIdx.x)*4;
    if (i >= n) return;
    float4 v = *(const float4*)&src[i];
    dst[i+0]=(bf16_t)v.x; dst[i+1]=(bf16_t)v.y; dst[i+2]=(bf16_t)v.z; dst[i+3]=(bf16_t)v.w;
}

// W_U [DM][DV] -> WUt [DV][DM] bf16 (tiled transpose)
__global__ __launch_bounds__(256) void k_trans_wu(const float* __restrict__ W,
                                                  bf16_t* __restrict__ out)
{
    __shared__ float tile[32][33];
    int n0 = blockIdx.x*32, k0 = blockIdx.y*32;
    int tx = threadIdx.x & 31, ty = threadIdx.x >> 5;
#pragma unroll
    for (int u=0;u<4;u++)
        tile[ty+u*8][tx] = W[(long)(k0+ty+u*8)*DV + n0+tx];
    __syncthreads();
#pragma unroll
    for (int u=0;u<4;u++)
        out[(long)(n0+ty+u*8)*DM + k0+tx] = (bf16_t)tile[tx][ty+u*8];
}

// ---------------------------------------------------------------------------
__global__ __launch_bounds__(256) void k_embed(const int* __restrict__ tok,
    const float* __restrict__ WE, const float* __restrict__ Wpos,
    float* __restrict__ xf, bf16_t* __restrict__ xb)
{
    int bp = blockIdx.x;
    int p  = bp & (S-1);
    int t  = tok[bp];
#pragma unroll
    for (int u=0;u<4;u++) {
        int d = u*256 + threadIdx.x;
        float v = WE[(long)d*DV + t] + Wpos[(long)p*DM + d];
        xf[(long)bp*DM + d] = v;
        xb[(long)bp*DM + d] = (bf16_t)v;
    }
}

// qkv_flat [b,p,3072] -> k[b,h,p,dh], vT[b,h,dh,p]  (q is read from qkv_flat)
__global__ __launch_bounds__(256) void k_permute_qkv(const bf16_t* __restrict__ qkv,
    bf16_t* __restrict__ k, bf16_t* __restrict__ vt)
{
    long idx = (long)blockIdx.x*256 + threadIdx.x;    // MTOK*3072
    int n = (int)(idx % 3072);
    long bp = idx / 3072;
    int b = (int)(bp >> 11), p = (int)(bp & 2047);
    int sel = n >> 10, m = n & 1023;
    int i = m >> 6, hh = m & 63;
    if (sel == 0) return;
    bf16_t v = qkv[idx];
    long bh = (long)b*NH + i;
    if (sel == 1) k[(bh*S + p)*DH + hh] = v;
    else          vt[(bh*DH + hh)*S + p] = v;
}

// ---------------------------------------------------------------------------
extern "C" void kernel_launch(void* const* d_in, const int* in_sizes, int n_in,
                              void* d_out, int out_size, void* d_ws, size_t ws_size,
                              hipStream_t stream)
{
    const int*   tokens = (const int*)d_in[0];
    const float* W_E    = (const float*)d_in[1];
    const float* W_pos  = (const float*)d_in[2];
    const float* W_K    = (const float*)d_in[3];
    const float* W_Q    = (const float*)d_in[4];
    const float* W_V    = (const float*)d_in[5];
    const float* W_O    = (const float*)d_in[6];
    const float* W_in   = (const float*)d_in[7];
    const float* b_in   = (const float*)d_in[8];
    const float* W_out  = (const float*)d_in[9];
    const float* b_out  = (const float*)d_in[10];
    const float* W_U    = (const float*)d_in[11];
    float* out = (float*)d_out;

    char* ws = (char*)d_ws;
    long off = 0;
    auto alloc = [&](long bytes)->char* {
        char* p = ws + off; off += (bytes + 255) & ~255L; return p;
    };
    bf16_t* wqkv = (bf16_t*)alloc((long)NL*3072*DM*2);
    bf16_t* wo   = (bf16_t*)alloc((long)NL*DM*DM*2);
    bf16_t* win  = (bf16_t*)alloc((long)NL*DMLP*DM*2);
    bf16_t* wout = (bf16_t*)alloc((long)NL*DM*DMLP*2);
    bf16_t* wut  = (bf16_t*)alloc((long)DV*DM*2);
    float*  xf   = (float*)alloc((long)MTOK*DM*4);
    bf16_t* xb   = (bf16_t*)alloc((long)MTOK*DM*2);
    bf16_t* qkvf = (bf16_t*)alloc((long)MTOK*3072*2);
    bf16_t* kb   = (bf16_t*)alloc((long)BATCH*NH*S*DH*2);
    bf16_t* vt   = (bf16_t*)alloc((long)BATCH*NH*S*DH*2);
    bf16_t* zf   = (bf16_t*)alloc((long)MTOK*DM*2);
    bf16_t* post = (bf16_t*)alloc((long)MTOK*DMLP*2);

    // --- weight conversion (per launch; deterministic) ---
    k_conv_qkv<<<(int)(((long)NL*3072*DM)/256), 256, 0, stream>>>(W_Q, W_K, W_V, wqkv);
    k_conv<<<(int)(((long)NL*DM*DM)/1024),   256, 0, stream>>>(W_O,   wo,   (long)NL*DM*DM);
    k_conv<<<(int)(((long)NL*DMLP*DM)/1024), 256, 0, stream>>>(W_in,  win,  (long)NL*DMLP*DM);
    k_conv<<<(int)(((long)NL*DM*DMLP)/1024), 256, 0, stream>>>(W_out, wout, (long)NL*DM*DMLP);
    k_trans_wu<<<dim3(DV/32, DM/32), 256, 0, stream>>>(W_U, wut);

    // --- embed ---
    k_embed<<<MTOK, 256, 0, stream>>>(tokens, W_E, W_pos, xf, xb);

    for (int l = 0; l < NL; ++l) {
        // QKV (fused N=3072)
        gemm_tn<128,128,0,false,false><<<dim3(MTOK/128, 3072/128, 1), 256, 0, stream>>>(
            xb, 0L, wqkv + (long)l*3072*DM, 0L, (char*)qkvf, 0L, 3072,
            nullptr, nullptr, nullptr, DM);
        k_permute_qkv<<<(int)(((long)MTOK*3072)/256), 256, 0, stream>>>(qkvf, kb, vt);

        // fused causal attention -> z_flat
        flash_attn<<<dim3(S/128, BATCH*NH), 256, 0, stream>>>(qkvf, kb, vt, zf);

        // attn_out = z_flat @ W_O^T, fused residual add into x
        gemm_tn<128,128,2,false,false><<<dim3(MTOK/128, DM/128, 1), 256, 0, stream>>>(
            zf, 0L, wo + (long)l*DM*DM, 0L, nullptr, 0L, DM,
            nullptr, xf, xb, DM);
        // MLP in: relu(x @ W_in^T + b_in)
        gemm_tn<128,128,0,true,true><<<dim3(MTOK/128, DMLP/128, 1), 256, 0, stream>>>(
            xb, 0L, win + (long)l*DMLP*DM, 0L, (char*)post, 0L, DMLP,
            b_in + (long)l*DMLP, nullptr, nullptr, DM);
        // MLP out + b_out, fused residual add into x
        gemm_tn<128,128,2,true,false><<<dim3(MTOK/128, DM/128, 1), 256, 0, stream>>>(
            post, 0L, wout + (long)l*DM*DMLP, 0L, nullptr, 0L, DM,
            b_out + (long)l*DM, xf, xb, DMLP);
    }

    // logits = x @ W_U  (f32 out)
    gemm_tn<128,128,1,false,false><<<dim3(MTOK/128, DV/128, 1), 256, 0, stream>>>(
        xb, 0L, wut, 0L, (char*)out, 0L, DV,
        nullptr, nullptr, nullptr, DM);
}

// Round 5
// 1881.669 us; speedup vs baseline: 2.0856x; 1.0192x over previous
//
#include <hip/hip_runtime.h>
#include <hip/hip_bf16.h>
#include <math.h>

// Model dims
#define DV   32000
#define DM   1024
#define DMLP 4096
#define DH   64
#define NH   16
#define NL   4
#define BATCH 2
#define S    2048
#define MTOK (BATCH*S)   // 4096 tokens

typedef __bf16 bf16_t;
typedef bf16_t bf16x8 __attribute__((ext_vector_type(8)));
typedef float  f32x4  __attribute__((ext_vector_type(4)));

#define AS1 __attribute__((address_space(1)))
#define AS3 __attribute__((address_space(3)))

__device__ __forceinline__ void gload16(const bf16_t* g, bf16_t* l) {
    __builtin_amdgcn_global_load_lds((const AS1 void*)g, (AS3 void*)l, 16, 0, 0);
}

__device__ __forceinline__ unsigned short bfbits(float v) {
    union { bf16_t b; unsigned short u; } c; c.b = (bf16_t)v; return c.u;
}

// ---------------------------------------------------------------------------
// Generic TN GEMM: C[M,N] = A[M,K] * B[N,K]^T, bf16 in, f32 accum.
// Grid: (M/BM, N/BN, Z). Block ids are XCD-chunk swizzled (bijective, m204):
// each XCD gets a contiguous run of ids = consecutive M-blocks over the same
// B panel -> panel stays in that XCD's L2.
// LDS: row-major [R][BK=64] (128B rows), 16B-chunk XOR swizzle
// phys = logical ^ (row&7) on stage-source and ds_read.
// MODE 0: write bf16 (optional bias/relu); MODE 1: write f32;
// MODE 2: resid_f32 += acc(+bias); residb_bf16 = bf16(resid)
// ---------------------------------------------------------------------------
template<int BM, int BN, int MODE, bool BIAS, bool RELU>
__global__ __launch_bounds__(256)
void gemm_tn(const bf16_t* __restrict__ A, long sA,
             const bf16_t* __restrict__ Bm, long sB,
             char* __restrict__ Out, long sC, int ldc,
             const float* __restrict__ bias,
             float* __restrict__ resid, bf16_t* __restrict__ residb,
             int K)
{
    constexpr int BK = 64;
    constexpr int WM = BM/2, WN = BN/2;
    constexpr int FM = WM/16, FN = WN/16;
    constexpr int APASS = (BM*BK)/(256*8);
    constexpr int BPASS = (BN*BK)/(256*8);

    // T1: bijective XCD-chunked swizzle
    const int nwg  = gridDim.x*gridDim.y;
    const int orig = blockIdx.y*gridDim.x + blockIdx.x;
    const int xcd  = orig & 7;
    const int qq   = nwg >> 3, rr = nwg & 7;
    const int wg   = (xcd < rr ? xcd*(qq+1) : rr*(qq+1) + (xcd-rr)*qq) + (orig >> 3);
    const int mb = wg % gridDim.x, nb = wg / gridDim.x;

    __shared__ alignas(16) bf16_t As[BM*BK];
    __shared__ alignas(16) bf16_t Bs[BN*BK];

    const int tid  = threadIdx.x;
    const int wave = tid >> 6, lane = tid & 63;
    const int wm = wave >> 1, wn = wave & 1;
    const int l16 = lane & 15, lh = lane >> 4;
    const long z = blockIdx.z;

    const bf16_t* Ab = A  + z*sA + (long)mb*BM*K;
    const bf16_t* Bb = Bm + z*sB + (long)nb*BN*K;

    f32x4 acc[FM][FN];
#pragma unroll
    for (int i=0;i<FM;i++)
#pragma unroll
        for (int j=0;j<FN;j++) { f32x4 zv = {0.f,0.f,0.f,0.f}; acc[i][j] = zv; }

    for (int k0 = 0; k0 < K; k0 += BK) {
        __syncthreads();
#pragma unroll
        for (int u=0; u<APASS; ++u) {
            int c = u*256 + tid;
            int row = c >> 3, lc = (c & 7) ^ (row & 7);
            gload16(&Ab[(long)row*K + k0 + lc*8], &As[c*8]);
        }
#pragma unroll
        for (int u=0; u<BPASS; ++u) {
            int c = u*256 + tid;
            int row = c >> 3, lc = (c & 7) ^ (row & 7);
            gload16(&Bb[(long)row*K + k0 + lc*8], &Bs[c*8]);
        }
        __syncthreads();

        bf16x8 af[FM][2], bfr[FN][2];
#pragma unroll
        for (int kk=0;kk<2;kk++) {
#pragma unroll
            for (int i=0;i<FM;i++) {
                int row = wm*WM + i*16 + l16;
                int pw = (kk*4 + lh) ^ (row & 7);
                af[i][kk] = *(const bf16x8*)&As[row*BK + pw*8];
            }
#pragma unroll
            for (int j=0;j<FN;j++) {
                int row = wn*WN + j*16 + l16;
                int pw = (kk*4 + lh) ^ (row & 7);
                bfr[j][kk] = *(const bf16x8*)&Bs[row*BK + pw*8];
            }
        }
#pragma unroll
        for (int kk=0;kk<2;kk++)
#pragma unroll
            for (int i=0;i<FM;i++)
#pragma unroll
                for (int j=0;j<FN;j++)
                    acc[i][j] = __builtin_amdgcn_mfma_f32_16x16x32_bf16(af[i][kk], bfr[j][kk], acc[i][j], 0,0,0);
    }

#pragma unroll
    for (int i=0;i<FM;i++) {
        int row0 = mb*BM + wm*WM + i*16 + lh*4;
#pragma unroll
        for (int j=0;j<FN;j++) {
            int col = nb*BN + wn*WN + j*16 + l16;
            float bv = BIAS ? bias[col] : 0.0f;
#pragma unroll
            for (int r=0;r<4;r++) {
                int row = row0 + r;
                float v = acc[i][j][r] + bv;
                if (RELU) v = v > 0.f ? v : 0.f;
                if constexpr (MODE == 0) {
                    long off = z*sC + (long)row*ldc + col;
                    ((bf16_t*)Out)[off] = (bf16_t)v;
                } else if constexpr (MODE == 1) {
                    long off = z*sC + (long)row*ldc + col;
                    ((float*)Out)[off] = v;
                } else {
                    long o2 = (long)row*ldc + col;
                    float nv = resid[o2] + v;
                    resid[o2]  = nv;
                    residb[o2] = (bf16_t)nv;
                }
            }
        }
    }
}

// ---------------------------------------------------------------------------
// Flash attention (causal). Grid: (S/128, BATCH*NH). 4 waves; each wave owns
// 32 q-rows. K is staged straight from qkvf (offset 1024 + hd*64, stride
// 3072); V^T from the permuted vt buffer. Swapped QK^T -> S^T[key][q];
// online softmax per q-column via shfl; P -> per-wave swizzled LDS;
// PV: mfma(V^T, P) -> O^T[dh][q]. Output -> z_flat [b,q,(head,dh)].
// ---------------------------------------------------------------------------
__global__ __launch_bounds__(256)
void flash_attn(const bf16_t* __restrict__ qkvf,  // [B][S][3072]
                const bf16_t* __restrict__ vtg,   // [BH][DH][S]
                bf16_t* __restrict__ zf)          // [B][S][DM]
{
    const int qt = blockIdx.x;           // q-tile (128 rows)
    const int bh = blockIdx.y;           // 0..31
    const int b  = bh >> 4, hd = bh & 15;

    __shared__ alignas(16) bf16_t Kl[64*64];
    __shared__ alignas(16) bf16_t Vtl[64*64];
    __shared__ alignas(16) bf16_t Pl[4*32*64];

    const int tid = threadIdx.x;
    const int wave = tid >> 6, lane = tid & 63;
    const int l16 = lane & 15, lh = lane >> 4;
    const int wq_lo = qt*128 + wave*32;          // this wave's first q row
    bf16_t* Pw = Pl + wave*32*64;

    // Q fragments: [qf][dh-half], B-operand layout
    bf16x8 qr[2][2];
#pragma unroll
    for (int qf=0; qf<2; qf++) {
        int qg = wq_lo + qf*16 + l16;
#pragma unroll
        for (int dhh=0; dhh<2; dhh++)
            qr[qf][dhh] = *(const bf16x8*)&qkvf[((long)b*S + qg)*3072 + hd*64 + dhh*32 + lh*8];
    }

    f32x4 o[4][2];                                // O^T acc [dh-frag][qf]
#pragma unroll
    for (int d=0; d<4; d++)
#pragma unroll
        for (int qf=0; qf<2; qf++) { f32x4 zv={0.f,0.f,0.f,0.f}; o[d][qf]=zv; }
    float mrun[2] = {-1e30f, -1e30f};
    float lrun[2] = {0.f, 0.f};

    const int nt = 2*(qt+1);                      // 64-key tiles needed
    const float C = 0.125f;                       // 1/sqrt(DH)

    for (int t = 0; t < nt; ++t) {
        const int kv0 = t*64;
        __syncthreads();
        // stage K tile [64 key][64 dh] (from qkvf, K at col 1024+hd*64)
#pragma unroll
        for (int u=0; u<2; ++u) {
            int c = u*256 + tid;
            int row = c >> 3, lc = (c & 7) ^ (row & 7);
            gload16(&qkvf[((long)b*S + kv0 + row)*3072 + 1024 + hd*64 + lc*8], &Kl[c*8]);
        }
        // stage V^T tile [64 dh][64 key]
#pragma unroll
        for (int u=0; u<2; ++u) {
            int c = u*256 + tid;
            int row = c >> 3, lc = (c & 7) ^ (row & 7);
            gload16(&vtg[((long)bh*DH + row)*S + kv0 + lc*8], &Vtl[c*8]);
        }
        __syncthreads();

        // ---- QK^T (swapped): s[f][qf] = S^T tile [key 16f..][q 16qf..]
        f32x4 s[4][2];
#pragma unroll
        for (int f=0; f<4; f++)
#pragma unroll
            for (int qf=0; qf<2; qf++) { f32x4 zv={0.f,0.f,0.f,0.f}; s[f][qf]=zv; }
        __builtin_amdgcn_s_setprio(1);
#pragma unroll
        for (int f=0; f<4; f++) {
            int krow = f*16 + l16;
#pragma unroll
            for (int dhh=0; dhh<2; dhh++) {
                bf16x8 kfr = *(const bf16x8*)&Kl[krow*64 + (((dhh*4+lh) ^ (krow&7))*8)];
#pragma unroll
                for (int qf=0; qf<2; qf++)
                    s[f][qf] = __builtin_amdgcn_mfma_f32_16x16x32_bf16(kfr, qr[qf][dhh], s[f][qf], 0,0,0);
            }
        }
        __builtin_amdgcn_s_setprio(0);

        const bool needmask = (kv0 + 64 > wq_lo);

        // ---- online softmax per qf (q = wq_lo + qf*16 + l16)
#pragma unroll
        for (int qf=0; qf<2; qf++) {
            int qg = wq_lo + qf*16 + l16;
            float pmax = -1e30f;
#pragma unroll
            for (int f=0; f<4; f++)
#pragma unroll
                for (int r=0; r<4; r++) {
                    float sv = s[f][qf][r];
                    if (needmask && (kv0 + f*16 + lh*4 + r > qg)) { sv = -1e30f; s[f][qf][r] = sv; }
                    pmax = fmaxf(pmax, sv);
                }
            pmax = fmaxf(pmax, __shfl_xor(pmax, 16));
            pmax = fmaxf(pmax, __shfl_xor(pmax, 32));
            float mnew = fmaxf(mrun[qf], pmax);
            float corr = __expf((mrun[qf] - mnew)*C);
            mrun[qf] = mnew;
            lrun[qf] *= corr;
#pragma unroll
            for (int d=0; d<4; d++) o[d][qf] *= corr;
            float lsum = 0.f;
            int qloc = qf*16 + l16;
#pragma unroll
            for (int f=0; f<4; f++) {
                ushort4 pk;
                float p0 = __expf((s[f][qf][0]-mnew)*C);
                float p1 = __expf((s[f][qf][1]-mnew)*C);
                float p2 = __expf((s[f][qf][2]-mnew)*C);
                float p3 = __expf((s[f][qf][3]-mnew)*C);
                lsum += (p0+p1) + (p2+p3);
                pk.x = bfbits(p0); pk.y = bfbits(p1); pk.z = bfbits(p2); pk.w = bfbits(p3);
                int phys = (f*2 + (lh>>1)) ^ (qloc & 7);
                *(ushort4*)&Pw[qloc*64 + phys*8 + (lh&1)*4] = pk;
            }
            lrun[qf] += lsum;
        }

        // ---- PV: o[d][qf] += V^T[dh][keys] * P^T[keys][q]
#pragma unroll
        for (int kh=0; kh<2; kh++) {
            bf16x8 pb[2];
#pragma unroll
            for (int qf=0; qf<2; qf++) {
                int qloc = qf*16 + l16;
                pb[qf] = *(const bf16x8*)&Pw[qloc*64 + (((kh*4+lh) ^ (qloc&7))*8)];
            }
            __builtin_amdgcn_s_setprio(1);
#pragma unroll
            for (int d=0; d<4; d++) {
                int vrow = d*16 + l16;
                bf16x8 va = *(const bf16x8*)&Vtl[vrow*64 + (((kh*4+lh) ^ (vrow&7))*8)];
#pragma unroll
                for (int qf=0; qf<2; qf++)
                    o[d][qf] = __builtin_amdgcn_mfma_f32_16x16x32_bf16(va, pb[qf], o[d][qf], 0,0,0);
            }
            __builtin_amdgcn_s_setprio(0);
        }
    }

    // ---- epilogue: normalize and write z_flat[b][q][hd*64 + dh]
#pragma unroll
    for (int qf=0; qf<2; qf++) {
        float lt = lrun[qf];
        lt += __shfl_xor(lt, 16);
        lt += __shfl_xor(lt, 32);
        float inv = 1.0f / lt;
        int qg = wq_lo + qf*16 + l16;
#pragma unroll
        for (int d=0; d<4; d++) {
            ushort4 ov;
            ov.x = bfbits(o[d][qf][0]*inv);
            ov.y = bfbits(o[d][qf][1]*inv);
            ov.z = bfbits(o[d][qf][2]*inv);
            ov.w = bfbits(o[d][qf][3]*inv);
            *(ushort4*)&zf[((long)b*S + qg)*DM + hd*64 + d*16 + lh*4] = ov;
        }
    }
}

// ---------------------------------------------------------------------------
// Weight conversion kernels
// ---------------------------------------------------------------------------
__global__ __launch_bounds__(256) void k_conv_qkv(
    const float* __restrict__ Wq, const float* __restrict__ Wk,
    const float* __restrict__ Wv, bf16_t* __restrict__ out)
{
    long idx = (long)blockIdx.x*256 + threadIdx.x;   // NL*3072*DM total
    long l = idx / (3072L*DM);
    long r = idx % (3072L*DM);
    int row = (int)(r / DM), d = (int)(r % DM);
    int sel = row >> 10, rr = row & 1023;
    const float* src = sel==0 ? Wq : (sel==1 ? Wk : Wv);
    out[idx] = (bf16_t)src[(l*1024 + rr)*(long)DM + d];
}

__global__ __launch_bounds__(256) void k_conv(const float* __restrict__ src,
                                              bf16_t* __restrict__ dst, long n)
{
    long i = ((long)blockIdx.x*256 + threadIdx.x)*4;
    if (i >= n) return;
    float4 v = *(const float4*)&src[i];
    dst[i+0]=(bf16_t)v.x; dst[i+1]=(bf16_t)v.y; dst[i+2]=(bf16_t)v.z; dst[i+3]=(bf16_t)v.w;
}

// W_U [DM][DV] -> WUt [DV][DM] bf16 (tiled transpose)
__global__ __launch_bounds__(256) void k_trans_wu(const float* __restrict__ W,
                                                  bf16_t* __restrict__ out)
{
    __shared__ float tile[32][33];
    int n0 = blockIdx.x*32, k0 = blockIdx.y*32;
    int tx = threadIdx.x & 31, ty = threadIdx.x >> 5;
#pragma unroll
    for (int u=0;u<4;u++)
        tile[ty+u*8][tx] = W[(long)(k0+ty+u*8)*DV + n0+tx];
    __syncthreads();
#pragma unroll
    for (int u=0;u<4;u++)
        out[(long)(n0+ty+u*8)*DM + k0+tx] = (bf16_t)tile[tx][ty+u*8];
}

// ---------------------------------------------------------------------------
__global__ __launch_bounds__(256) void k_embed(const int* __restrict__ tok,
    const float* __restrict__ WE, const float* __restrict__ Wpos,
    float* __restrict__ xf, bf16_t* __restrict__ xb)
{
    int bp = blockIdx.x;
    int p  = bp & (S-1);
    int t  = tok[bp];
#pragma unroll
    for (int u=0;u<4;u++) {
        int d = u*256 + threadIdx.x;
        float v = WE[(long)d*DV + t] + Wpos[(long)p*DM + d];
        xf[(long)bp*DM + d] = v;
        xb[(long)bp*DM + d] = (bf16_t)v;
    }
}

// qkv_flat [b,p,3072] (V part only) -> vT[b,h,dh,p]
__global__ __launch_bounds__(256) void k_permute_v(const bf16_t* __restrict__ qkv,
    bf16_t* __restrict__ vt)
{
    long idx = (long)blockIdx.x*256 + threadIdx.x;    // MTOK*1024
    long bp = idx >> 10; int m = (int)(idx & 1023);
    int b = (int)(bp >> 11), p = (int)(bp & 2047);
    int i = m >> 6, hh = m & 63;
    vt[(((long)b*NH + i)*DH + hh)*S + p] = qkv[bp*3072 + 2048 + m];
}

// ---------------------------------------------------------------------------
extern "C" void kernel_launch(void* const* d_in, const int* in_sizes, int n_in,
                              void* d_out, int out_size, void* d_ws, size_t ws_size,
                              hipStream_t stream)
{
    const int*   tokens = (const int*)d_in[0];
    const float* W_E    = (const float*)d_in[1];
    const float* W_pos  = (const float*)d_in[2];
    const float* W_K    = (const float*)d_in[3];
    const float* W_Q    = (const float*)d_in[4];
    const float* W_V    = (const float*)d_in[5];
    const float* W_O    = (const float*)d_in[6];
    const float* W_in   = (const float*)d_in[7];
    const float* b_in   = (const float*)d_in[8];
    const float* W_out  = (const float*)d_in[9];
    const float* b_out  = (const float*)d_in[10];
    const float* W_U    = (const float*)d_in[11];
    float* out = (float*)d_out;

    char* ws = (char*)d_ws;
    long off = 0;
    auto alloc = [&](long bytes)->char* {
        char* p = ws + off; off += (bytes + 255) & ~255L; return p;
    };
    bf16_t* wqkv = (bf16_t*)alloc((long)NL*3072*DM*2);
    bf16_t* wo   = (bf16_t*)alloc((long)NL*DM*DM*2);
    bf16_t* win  = (bf16_t*)alloc((long)NL*DMLP*DM*2);
    bf16_t* wout = (bf16_t*)alloc((long)NL*DM*DMLP*2);
    bf16_t* wut  = (bf16_t*)alloc((long)DV*DM*2);
    float*  xf   = (float*)alloc((long)MTOK*DM*4);
    bf16_t* xb   = (bf16_t*)alloc((long)MTOK*DM*2);
    bf16_t* qkvf = (bf16_t*)alloc((long)MTOK*3072*2);
    bf16_t* vt   = (bf16_t*)alloc((long)BATCH*NH*S*DH*2);
    bf16_t* zf   = (bf16_t*)alloc((long)MTOK*DM*2);
    bf16_t* post = (bf16_t*)alloc((long)MTOK*DMLP*2);

    // --- weight conversion (per launch; deterministic) ---
    k_conv_qkv<<<(int)(((long)NL*3072*DM)/256), 256, 0, stream>>>(W_Q, W_K, W_V, wqkv);
    k_conv<<<(int)(((long)NL*DM*DM)/1024),   256, 0, stream>>>(W_O,   wo,   (long)NL*DM*DM);
    k_conv<<<(int)(((long)NL*DMLP*DM)/1024), 256, 0, stream>>>(W_in,  win,  (long)NL*DMLP*DM);
    k_conv<<<(int)(((long)NL*DM*DMLP)/1024), 256, 0, stream>>>(W_out, wout, (long)NL*DM*DMLP);
    k_trans_wu<<<dim3(DV/32, DM/32), 256, 0, stream>>>(W_U, wut);

    // --- embed ---
    k_embed<<<MTOK, 256, 0, stream>>>(tokens, W_E, W_pos, xf, xb);

    for (int l = 0; l < NL; ++l) {
        // QKV (fused N=3072)
        gemm_tn<128,128,0,false,false><<<dim3(MTOK/128, 3072/128, 1), 256, 0, stream>>>(
            xb, 0L, wqkv + (long)l*3072*DM, 0L, (char*)qkvf, 0L, 3072,
            nullptr, nullptr, nullptr, DM);
        k_permute_v<<<(int)(((long)MTOK*1024)/256), 256, 0, stream>>>(qkvf, vt);

        // fused causal attention -> z_flat
        flash_attn<<<dim3(S/128, BATCH*NH), 256, 0, stream>>>(qkvf, vt, zf);

        // attn_out = z_flat @ W_O^T, fused residual add into x  (64x128 tile)
        gemm_tn<64,128,2,false,false><<<dim3(MTOK/64, DM/128, 1), 256, 0, stream>>>(
            zf, 0L, wo + (long)l*DM*DM, 0L, nullptr, 0L, DM,
            nullptr, xf, xb, DM);
        // MLP in: relu(x @ W_in^T + b_in)
        gemm_tn<128,128,0,true,true><<<dim3(MTOK/128, DMLP/128, 1), 256, 0, stream>>>(
            xb, 0L, win + (long)l*DMLP*DM, 0L, (char*)post, 0L, DMLP,
            b_in + (long)l*DMLP, nullptr, nullptr, DM);
        // MLP out + b_out, fused residual add into x  (64x128 tile)
        gemm_tn<64,128,2,true,false><<<dim3(MTOK/64, DM/128, 1), 256, 0, stream>>>(
            post, 0L, wout + (long)l*DM*DMLP, 0L, nullptr, 0L, DM,
            b_out + (long)l*DM, xf, xb, DMLP);
    }

    // logits = x @ W_U  (f32 out)
    gemm_tn<128,128,1,false,false><<<dim3(MTOK/128, DV/128, 1), 256, 0, stream>>>(
        xb, 0L, wut, 0L, (char*)out, 0L, DV,
        nullptr, nullptr, nullptr, DM);
}

// Round 6
// 1670.207 us; speedup vs baseline: 2.3497x; 1.1266x over previous
//
#include <hip/hip_runtime.h>
#include <hip/hip_bf16.h>
#include <math.h>

// Model dims
#define DV   32000
#define DM   1024
#define DMLP 4096
#define DH   64
#define NH   16
#define NL   4
#define BATCH 2
#define S    2048
#define MTOK (BATCH*S)   // 4096 tokens

typedef __bf16 bf16_t;
typedef bf16_t bf16x8 __attribute__((ext_vector_type(8)));
typedef float  f32x4  __attribute__((ext_vector_type(4)));

#define AS1 __attribute__((address_space(1)))
#define AS3 __attribute__((address_space(3)))

__device__ __forceinline__ void gload16(const bf16_t* g, bf16_t* l) {
    __builtin_amdgcn_global_load_lds((const AS1 void*)g, (AS3 void*)l, 16, 0, 0);
}

__device__ __forceinline__ unsigned short bfbits(float v) {
    union { bf16_t b; unsigned short u; } c; c.b = (bf16_t)v; return c.u;
}

// ---------------------------------------------------------------------------
// 256x256 deep-pipelined TN GEMM: C[M,N] = A[M,K] * B[N,K]^T.
// 512 threads = 8 waves (2M x 4N); per-wave output 128x64 (acc[8][4]).
// LDS 128 KiB: [2 buf][A,B][2 half][128x64 bf16], chunk-XOR swizzled
// (phys16Bchunk = logical ^ (row&7), same involution on stage-src & ds_read).
// Schedule per K-tile (BK=64): phase0 issues next-tile A-half0 prefetch THEN
// waits vmcnt(2) (all current-tile loads landed, prefetch stays in flight)
// + barrier; phases 0-3 each issue one more half-tile prefetch and run a
// 16-MFMA setprio cluster; one end barrier. vmcnt never drains in-loop (T4).
// MODE 0: bf16 out (+bias/relu); MODE 1: f32 out.
// Requires M%256==0, N%256==0, K%64==0.
// ---------------------------------------------------------------------------
template<int MODE, bool BIAS, bool RELU>
__global__ __launch_bounds__(512, 1)
void gemm256(const bf16_t* __restrict__ A, const bf16_t* __restrict__ Bm,
             char* __restrict__ Out, int ldc,
             const float* __restrict__ bias, int K)
{
    const int mb = blockIdx.x, nb = blockIdx.y;

    __shared__ alignas(16) bf16_t lds[2][2][2][128*64];

    const int tid  = threadIdx.x;
    const int wave = tid >> 6, lane = tid & 63;
    const int wm = wave >> 2, wn = wave & 3;     // 2 x 4 waves
    const int l16 = lane & 15, lh = lane >> 4;

    const bf16_t* Abase = A  + (long)(mb*256)*K;
    const bf16_t* Bbase = Bm + (long)(nb*256)*K;

    // staging coords: 2 x 16B chunks per thread per half-tile (128x64)
    const int c0 = tid,      r0 = c0 >> 3, lc0 = (c0 & 7) ^ (r0 & 7);
    const int c1 = 512 + tid,r1 = c1 >> 3, lc1 = (c1 & 7) ^ (r1 & 7);

    auto stage = [&](int buf, int mat, int half, int k0) {
        const bf16_t* src = (mat ? Bbase : Abase) + (long)(half*128)*K + k0;
        bf16_t* dst = &lds[buf][mat][half][0];
        gload16(&src[(long)r0*K + lc0*8], dst + c0*8);
        gload16(&src[(long)r1*K + lc1*8], dst + c1*8);
    };

    f32x4 acc[8][4];
#pragma unroll
    for (int i=0;i<8;i++)
#pragma unroll
        for (int j=0;j<4;j++) { f32x4 zv={0.f,0.f,0.f,0.f}; acc[i][j]=zv; }

    const int NT = K >> 6;
    // prologue: tile 0 -> buf 0
    stage(0,0,0,0); stage(0,0,1,0); stage(0,1,0,0); stage(0,1,1,0);

    int cur = 0;
    for (int kt = 0; kt < NT; ++kt) {
        const int nxt = cur ^ 1;
        const int k1 = (kt+1) << 6;
        const bool more = (kt+1 < NT);

        // ---- phase 0: prefetch A-half0(next); counted wait; sync; m0-3 x n0-1
        if (more) {
            stage(nxt,0,0,k1);
            asm volatile("s_waitcnt vmcnt(2)" ::: "memory");
        } else {
            asm volatile("s_waitcnt vmcnt(0)" ::: "memory");
        }
        asm volatile("s_barrier" ::: "memory");

        bf16x8 af[4][2], bfr[4][2];
#pragma unroll
        for (int i=0;i<4;i++) {
            int ra = i*16 + l16;
#pragma unroll
            for (int kk=0;kk<2;kk++)
                af[i][kk] = *(const bf16x8*)&lds[cur][0][wm][ra*64 + (((kk*4+lh)^(ra&7))*8)];
        }
#pragma unroll
        for (int j=0;j<2;j++) {
            int rb = (wn&1)*64 + j*16 + l16;
#pragma unroll
            for (int kk=0;kk<2;kk++)
                bfr[j][kk] = *(const bf16x8*)&lds[cur][1][wn>>1][rb*64 + (((kk*4+lh)^(rb&7))*8)];
        }
        __builtin_amdgcn_s_setprio(1);
#pragma unroll
        for (int kk=0;kk<2;kk++)
#pragma unroll
            for (int i=0;i<4;i++)
#pragma unroll
                for (int j=0;j<2;j++)
                    acc[i][j] = __builtin_amdgcn_mfma_f32_16x16x32_bf16(af[i][kk], bfr[j][kk], acc[i][j], 0,0,0);
        __builtin_amdgcn_s_setprio(0);

        // ---- phase 1: prefetch A-half1(next); m0-3 x n2-3
        if (more) stage(nxt,0,1,k1);
#pragma unroll
        for (int j=2;j<4;j++) {
            int rb = (wn&1)*64 + j*16 + l16;
#pragma unroll
            for (int kk=0;kk<2;kk++)
                bfr[j][kk] = *(const bf16x8*)&lds[cur][1][wn>>1][rb*64 + (((kk*4+lh)^(rb&7))*8)];
        }
        __builtin_amdgcn_s_setprio(1);
#pragma unroll
        for (int kk=0;kk<2;kk++)
#pragma unroll
            for (int i=0;i<4;i++)
#pragma unroll
                for (int j=2;j<4;j++)
                    acc[i][j] = __builtin_amdgcn_mfma_f32_16x16x32_bf16(af[i][kk], bfr[j][kk], acc[i][j], 0,0,0);
        __builtin_amdgcn_s_setprio(0);

        // ---- phase 2: prefetch B-half0(next); m4-7 x n0-1 (reuse af regs)
        if (more) stage(nxt,1,0,k1);
#pragma unroll
        for (int i=0;i<4;i++) {
            int ra = (i+4)*16 + l16;
#pragma unroll
            for (int kk=0;kk<2;kk++)
                af[i][kk] = *(const bf16x8*)&lds[cur][0][wm][ra*64 + (((kk*4+lh)^(ra&7))*8)];
        }
        __builtin_amdgcn_s_setprio(1);
#pragma unroll
        for (int kk=0;kk<2;kk++)
#pragma unroll
            for (int i=0;i<4;i++)
#pragma unroll
                for (int j=0;j<2;j++)
                    acc[i+4][j] = __builtin_amdgcn_mfma_f32_16x16x32_bf16(af[i][kk], bfr[j][kk], acc[i+4][j], 0,0,0);
        __builtin_amdgcn_s_setprio(0);

        // ---- phase 3: prefetch B-half1(next); m4-7 x n2-3
        if (more) stage(nxt,1,1,k1);
        __builtin_amdgcn_s_setprio(1);
#pragma unroll
        for (int kk=0;kk<2;kk++)
#pragma unroll
            for (int i=0;i<4;i++)
#pragma unroll
                for (int j=2;j<4;j++)
                    acc[i+4][j] = __builtin_amdgcn_mfma_f32_16x16x32_bf16(af[i][kk], bfr[j][kk], acc[i+4][j], 0,0,0);
        __builtin_amdgcn_s_setprio(0);

        asm volatile("s_barrier" ::: "memory");   // all waves done with buf[cur]
        cur = nxt;
    }

    // epilogue: C/D layout col=lane&15, row=(lane>>4)*4+reg
#pragma unroll
    for (int i=0;i<8;i++) {
        int row0 = mb*256 + wm*128 + i*16 + lh*4;
#pragma unroll
        for (int j=0;j<4;j++) {
            int col = nb*256 + wn*64 + j*16 + l16;
            float bv = BIAS ? bias[col] : 0.0f;
#pragma unroll
            for (int r=0;r<4;r++) {
                int row = row0 + r;
                float v = acc[i][j][r] + bv;
                if (RELU) v = v > 0.f ? v : 0.f;
                if constexpr (MODE == 0)
                    ((bf16_t*)Out)[(long)row*ldc + col] = (bf16_t)v;
                else
                    ((float*)Out)[(long)row*ldc + col] = v;
            }
        }
    }
}

// ---------------------------------------------------------------------------
// 128-class TN GEMM (kept for N=1024 ops). No XCD swizzle (round-5 A/B:
// swizzle raised unembed FETCH 301->828 MB; dispatch order already shares
// panels across XCDs here).
// MODE 0: bf16 out (+bias/relu); MODE 1: f32 out; MODE 2: residual add.
// ---------------------------------------------------------------------------
template<int BM, int BN, int MODE, bool BIAS, bool RELU>
__global__ __launch_bounds__(256)
void gemm_tn(const bf16_t* __restrict__ A, long sA,
             const bf16_t* __restrict__ Bm, long sB,
             char* __restrict__ Out, long sC, int ldc,
             const float* __restrict__ bias,
             float* __restrict__ resid, bf16_t* __restrict__ residb,
             int K)
{
    constexpr int BK = 64;
    constexpr int WM = BM/2, WN = BN/2;
    constexpr int FM = WM/16, FN = WN/16;
    constexpr int APASS = (BM*BK)/(256*8);
    constexpr int BPASS = (BN*BK)/(256*8);

    const int mb = blockIdx.x, nb = blockIdx.y;

    __shared__ alignas(16) bf16_t As[BM*BK];
    __shared__ alignas(16) bf16_t Bs[BN*BK];

    const int tid  = threadIdx.x;
    const int wave = tid >> 6, lane = tid & 63;
    const int wm = wave >> 1, wn = wave & 1;
    const int l16 = lane & 15, lh = lane >> 4;
    const long z = blockIdx.z;

    const bf16_t* Ab = A  + z*sA + (long)mb*BM*K;
    const bf16_t* Bb = Bm + z*sB + (long)nb*BN*K;

    f32x4 acc[FM][FN];
#pragma unroll
    for (int i=0;i<FM;i++)
#pragma unroll
        for (int j=0;j<FN;j++) { f32x4 zv = {0.f,0.f,0.f,0.f}; acc[i][j] = zv; }

    for (int k0 = 0; k0 < K; k0 += BK) {
        __syncthreads();
#pragma unroll
        for (int u=0; u<APASS; ++u) {
            int c = u*256 + tid;
            int row = c >> 3, lc = (c & 7) ^ (row & 7);
            gload16(&Ab[(long)row*K + k0 + lc*8], &As[c*8]);
        }
#pragma unroll
        for (int u=0; u<BPASS; ++u) {
            int c = u*256 + tid;
            int row = c >> 3, lc = (c & 7) ^ (row & 7);
            gload16(&Bb[(long)row*K + k0 + lc*8], &Bs[c*8]);
        }
        __syncthreads();

        bf16x8 af[FM][2], bfr[FN][2];
#pragma unroll
        for (int kk=0;kk<2;kk++) {
#pragma unroll
            for (int i=0;i<FM;i++) {
                int row = wm*WM + i*16 + l16;
                int pw = (kk*4 + lh) ^ (row & 7);
                af[i][kk] = *(const bf16x8*)&As[row*BK + pw*8];
            }
#pragma unroll
            for (int j=0;j<FN;j++) {
                int row = wn*WN + j*16 + l16;
                int pw = (kk*4 + lh) ^ (row & 7);
                bfr[j][kk] = *(const bf16x8*)&Bs[row*BK + pw*8];
            }
        }
#pragma unroll
        for (int kk=0;kk<2;kk++)
#pragma unroll
            for (int i=0;i<FM;i++)
#pragma unroll
                for (int j=0;j<FN;j++)
                    acc[i][j] = __builtin_amdgcn_mfma_f32_16x16x32_bf16(af[i][kk], bfr[j][kk], acc[i][j], 0,0,0);
    }

#pragma unroll
    for (int i=0;i<FM;i++) {
        int row0 = mb*BM + wm*WM + i*16 + lh*4;
#pragma unroll
        for (int j=0;j<FN;j++) {
            int col = nb*BN + wn*WN + j*16 + l16;
            float bv = BIAS ? bias[col] : 0.0f;
#pragma unroll
            for (int r=0;r<4;r++) {
                int row = row0 + r;
                float v = acc[i][j][r] + bv;
                if (RELU) v = v > 0.f ? v : 0.f;
                if constexpr (MODE == 0) {
                    long off = z*sC + (long)row*ldc + col;
                    ((bf16_t*)Out)[off] = (bf16_t)v;
                } else if constexpr (MODE == 1) {
                    long off = z*sC + (long)row*ldc + col;
                    ((float*)Out)[off] = v;
                } else {
                    long o2 = (long)row*ldc + col;
                    float nv = resid[o2] + v;
                    resid[o2]  = nv;
                    residb[o2] = (bf16_t)nv;
                }
            }
        }
    }
}

// ---------------------------------------------------------------------------
// Flash attention (causal). Grid: (S/128, BATCH*NH). 4 waves; each wave owns
// 32 q-rows. K staged straight from qkvf; V^T from vt. Swapped QK^T ->
// S^T[key][q]; online softmax per q-column via shfl; P -> per-wave swizzled
// LDS; PV: mfma(V^T, P) -> O^T[dh][q]. Output -> z_flat [b,q,(head,dh)].
// ---------------------------------------------------------------------------
__global__ __launch_bounds__(256)
void flash_attn(const bf16_t* __restrict__ qkvf,  // [B][S][3072]
                const bf16_t* __restrict__ vtg,   // [BH][DH][S]
                bf16_t* __restrict__ zf)          // [B][S][DM]
{
    const int qt = blockIdx.x;
    const int bh = blockIdx.y;
    const int b  = bh >> 4, hd = bh & 15;

    __shared__ alignas(16) bf16_t Kl[64*64];
    __shared__ alignas(16) bf16_t Vtl[64*64];
    __shared__ alignas(16) bf16_t Pl[4*32*64];

    const int tid = threadIdx.x;
    const int wave = tid >> 6, lane = tid & 63;
    const int l16 = lane & 15, lh = lane >> 4;
    const int wq_lo = qt*128 + wave*32;
    bf16_t* Pw = Pl + wave*32*64;

    bf16x8 qr[2][2];
#pragma unroll
    for (int qf=0; qf<2; qf++) {
        int qg = wq_lo + qf*16 + l16;
#pragma unroll
        for (int dhh=0; dhh<2; dhh++)
            qr[qf][dhh] = *(const bf16x8*)&qkvf[((long)b*S + qg)*3072 + hd*64 + dhh*32 + lh*8];
    }

    f32x4 o[4][2];
#pragma unroll
    for (int d=0; d<4; d++)
#pragma unroll
        for (int qf=0; qf<2; qf++) { f32x4 zv={0.f,0.f,0.f,0.f}; o[d][qf]=zv; }
    float mrun[2] = {-1e30f, -1e30f};
    float lrun[2] = {0.f, 0.f};

    const int nt = 2*(qt+1);
    const float C = 0.125f;

    for (int t = 0; t < nt; ++t) {
        const int kv0 = t*64;
        __syncthreads();
#pragma unroll
        for (int u=0; u<2; ++u) {
            int c = u*256 + tid;
            int row = c >> 3, lc = (c & 7) ^ (row & 7);
            gload16(&qkvf[((long)b*S + kv0 + row)*3072 + 1024 + hd*64 + lc*8], &Kl[c*8]);
        }
#pragma unroll
        for (int u=0; u<2; ++u) {
            int c = u*256 + tid;
            int row = c >> 3, lc = (c & 7) ^ (row & 7);
            gload16(&vtg[((long)bh*DH + row)*S + kv0 + lc*8], &Vtl[c*8]);
        }
        __syncthreads();

        f32x4 s[4][2];
#pragma unroll
        for (int f=0; f<4; f++)
#pragma unroll
            for (int qf=0; qf<2; qf++) { f32x4 zv={0.f,0.f,0.f,0.f}; s[f][qf]=zv; }
        __builtin_amdgcn_s_setprio(1);
#pragma unroll
        for (int f=0; f<4; f++) {
            int krow = f*16 + l16;
#pragma unroll
            for (int dhh=0; dhh<2; dhh++) {
                bf16x8 kfr = *(const bf16x8*)&Kl[krow*64 + (((dhh*4+lh) ^ (krow&7))*8)];
#pragma unroll
                for (int qf=0; qf<2; qf++)
                    s[f][qf] = __builtin_amdgcn_mfma_f32_16x16x32_bf16(kfr, qr[qf][dhh], s[f][qf], 0,0,0);
            }
        }
        __builtin_amdgcn_s_setprio(0);

        const bool needmask = (kv0 + 64 > wq_lo);

#pragma unroll
        for (int qf=0; qf<2; qf++) {
            int qg = wq_lo + qf*16 + l16;
            float pmax = -1e30f;
#pragma unroll
            for (int f=0; f<4; f++)
#pragma unroll
                for (int r=0; r<4; r++) {
                    float sv = s[f][qf][r];
                    if (needmask && (kv0 + f*16 + lh*4 + r > qg)) { sv = -1e30f; s[f][qf][r] = sv; }
                    pmax = fmaxf(pmax, sv);
                }
            pmax = fmaxf(pmax, __shfl_xor(pmax, 16));
            pmax = fmaxf(pmax, __shfl_xor(pmax, 32));
            float mnew = fmaxf(mrun[qf], pmax);
            float corr = __expf((mrun[qf] - mnew)*C);
            mrun[qf] = mnew;
            lrun[qf] *= corr;
#pragma unroll
            for (int d=0; d<4; d++) o[d][qf] *= corr;
            float lsum = 0.f;
            int qloc = qf*16 + l16;
#pragma unroll
            for (int f=0; f<4; f++) {
                ushort4 pk;
                float p0 = __expf((s[f][qf][0]-mnew)*C);
                float p1 = __expf((s[f][qf][1]-mnew)*C);
                float p2 = __expf((s[f][qf][2]-mnew)*C);
                float p3 = __expf((s[f][qf][3]-mnew)*C);
                lsum += (p0+p1) + (p2+p3);
                pk.x = bfbits(p0); pk.y = bfbits(p1); pk.z = bfbits(p2); pk.w = bfbits(p3);
                int phys = (f*2 + (lh>>1)) ^ (qloc & 7);
                *(ushort4*)&Pw[qloc*64 + phys*8 + (lh&1)*4] = pk;
            }
            lrun[qf] += lsum;
        }

#pragma unroll
        for (int kh=0; kh<2; kh++) {
            bf16x8 pb[2];
#pragma unroll
            for (int qf=0; qf<2; qf++) {
                int qloc = qf*16 + l16;
                pb[qf] = *(const bf16x8*)&Pw[qloc*64 + (((kh*4+lh) ^ (qloc&7))*8)];
            }
            __builtin_amdgcn_s_setprio(1);
#pragma unroll
            for (int d=0; d<4; d++) {
                int vrow = d*16 + l16;
                bf16x8 va = *(const bf16x8*)&Vtl[vrow*64 + (((kh*4+lh) ^ (vrow&7))*8)];
#pragma unroll
                for (int qf=0; qf<2; qf++)
                    o[d][qf] = __builtin_amdgcn_mfma_f32_16x16x32_bf16(va, pb[qf], o[d][qf], 0,0,0);
            }
            __builtin_amdgcn_s_setprio(0);
        }
    }

#pragma unroll
    for (int qf=0; qf<2; qf++) {
        float lt = lrun[qf];
        lt += __shfl_xor(lt, 16);
        lt += __shfl_xor(lt, 32);
        float inv = 1.0f / lt;
        int qg = wq_lo + qf*16 + l16;
#pragma unroll
        for (int d=0; d<4; d++) {
            ushort4 ov;
            ov.x = bfbits(o[d][qf][0]*inv);
            ov.y = bfbits(o[d][qf][1]*inv);
            ov.z = bfbits(o[d][qf][2]*inv);
            ov.w = bfbits(o[d][qf][3]*inv);
            *(ushort4*)&zf[((long)b*S + qg)*DM + hd*64 + d*16 + lh*4] = ov;
        }
    }
}

// ---------------------------------------------------------------------------
// Weight conversion kernels
// ---------------------------------------------------------------------------
__global__ __launch_bounds__(256) void k_conv_qkv(
    const float* __restrict__ Wq, const float* __restrict__ Wk,
    const float* __restrict__ Wv, bf16_t* __restrict__ out)
{
    long idx = (long)blockIdx.x*256 + threadIdx.x;
    long l = idx / (3072L*DM);
    long r = idx % (3072L*DM);
    int row = (int)(r / DM), d = (int)(r % DM);
    int sel = row >> 10, rr = row & 1023;
    const float* src = sel==0 ? Wq : (sel==1 ? Wk : Wv);
    out[idx] = (bf16_t)src[(l*1024 + rr)*(long)DM + d];
}

__global__ __launch_bounds__(256) void k_conv(const float* __restrict__ src,
                                              bf16_t* __restrict__ dst, long n)
{
    long i = ((long)blockIdx.x*256 + threadIdx.x)*4;
    if (i >= n) return;
    float4 v = *(const float4*)&src[i];
    dst[i+0]=(bf16_t)v.x; dst[i+1]=(bf16_t)v.y; dst[i+2]=(bf16_t)v.z; dst[i+3]=(bf16_t)v.w;
}

// W_U [DM][DV] -> WUt [DV][DM] bf16 (tiled transpose)
__global__ __launch_bounds__(256) void k_trans_wu(const float* __restrict__ W,
                                                  bf16_t* __restrict__ out)
{
    __shared__ float tile[32][33];
    int n0 = blockIdx.x*32, k0 = blockIdx.y*32;
    int tx = threadIdx.x & 31, ty = threadIdx.x >> 5;
#pragma unroll
    for (int u=0;u<4;u++)
        tile[ty+u*8][tx] = W[(long)(k0+ty+u*8)*DV + n0+tx];
    __syncthreads();
#pragma unroll
    for (int u=0;u<4;u++)
        out[(long)(n0+ty+u*8)*DM + k0+tx] = (bf16_t)tile[tx][ty+u*8];
}

// ---------------------------------------------------------------------------
__global__ __launch_bounds__(256) void k_embed(const int* __restrict__ tok,
    const float* __restrict__ WE, const float* __restrict__ Wpos,
    float* __restrict__ xf, bf16_t* __restrict__ xb)
{
    int bp = blockIdx.x;
    int p  = bp & (S-1);
    int t  = tok[bp];
#pragma unroll
    for (int u=0;u<4;u++) {
        int d = u*256 + threadIdx.x;
        float v = WE[(long)d*DV + t] + Wpos[(long)p*DM + d];
        xf[(long)bp*DM + d] = v;
        xb[(long)bp*DM + d] = (bf16_t)v;
    }
}

// qkv_flat [b,p,3072] (V part only) -> vT[b,h,dh,p]
__global__ __launch_bounds__(256) void k_permute_v(const bf16_t* __restrict__ qkv,
    bf16_t* __restrict__ vt)
{
    long idx = (long)blockIdx.x*256 + threadIdx.x;
    long bp = idx >> 10; int m = (int)(idx & 1023);
    int b = (int)(bp >> 11), p = (int)(bp & 2047);
    int i = m >> 6, hh = m & 63;
    vt[(((long)b*NH + i)*DH + hh)*S + p] = qkv[bp*3072 + 2048 + m];
}

// ---------------------------------------------------------------------------
extern "C" void kernel_launch(void* const* d_in, const int* in_sizes, int n_in,
                              void* d_out, int out_size, void* d_ws, size_t ws_size,
                              hipStream_t stream)
{
    const int*   tokens = (const int*)d_in[0];
    const float* W_E    = (const float*)d_in[1];
    const float* W_pos  = (const float*)d_in[2];
    const float* W_K    = (const float*)d_in[3];
    const float* W_Q    = (const float*)d_in[4];
    const float* W_V    = (const float*)d_in[5];
    const float* W_O    = (const float*)d_in[6];
    const float* W_in   = (const float*)d_in[7];
    const float* b_in   = (const float*)d_in[8];
    const float* W_out  = (const float*)d_in[9];
    const float* b_out  = (const float*)d_in[10];
    const float* W_U    = (const float*)d_in[11];
    float* out = (float*)d_out;

    char* ws = (char*)d_ws;
    long off = 0;
    auto alloc = [&](long bytes)->char* {
        char* p = ws + off; off += (bytes + 255) & ~255L; return p;
    };
    bf16_t* wqkv = (bf16_t*)alloc((long)NL*3072*DM*2);
    bf16_t* wo   = (bf16_t*)alloc((long)NL*DM*DM*2);
    bf16_t* win  = (bf16_t*)alloc((long)NL*DMLP*DM*2);
    bf16_t* wout = (bf16_t*)alloc((long)NL*DM*DMLP*2);
    bf16_t* wut  = (bf16_t*)alloc((long)DV*DM*2);
    float*  xf   = (float*)alloc((long)MTOK*DM*4);
    bf16_t* xb   = (bf16_t*)alloc((long)MTOK*DM*2);
    bf16_t* qkvf = (bf16_t*)alloc((long)MTOK*3072*2);
    bf16_t* vt   = (bf16_t*)alloc((long)BATCH*NH*S*DH*2);
    bf16_t* zf   = (bf16_t*)alloc((long)MTOK*DM*2);
    bf16_t* post = (bf16_t*)alloc((long)MTOK*DMLP*2);

    // --- weight conversion (per launch; deterministic) ---
    k_conv_qkv<<<(int)(((long)NL*3072*DM)/256), 256, 0, stream>>>(W_Q, W_K, W_V, wqkv);
    k_conv<<<(int)(((long)NL*DM*DM)/1024),   256, 0, stream>>>(W_O,   wo,   (long)NL*DM*DM);
    k_conv<<<(int)(((long)NL*DMLP*DM)/1024), 256, 0, stream>>>(W_in,  win,  (long)NL*DMLP*DM);
    k_conv<<<(int)(((long)NL*DM*DMLP)/1024), 256, 0, stream>>>(W_out, wout, (long)NL*DM*DMLP);
    k_trans_wu<<<dim3(DV/32, DM/32), 256, 0, stream>>>(W_U, wut);

    // --- embed ---
    k_embed<<<MTOK, 256, 0, stream>>>(tokens, W_E, W_pos, xf, xb);

    for (int l = 0; l < NL; ++l) {
        // QKV (fused N=3072): 256x256 pipelined kernel
        gemm256<0,false,false><<<dim3(MTOK/256, 3072/256), 512, 0, stream>>>(
            xb, wqkv + (long)l*3072*DM, (char*)qkvf, 3072, nullptr, DM);
        k_permute_v<<<(int)(((long)MTOK*1024)/256), 256, 0, stream>>>(qkvf, vt);

        // fused causal attention -> z_flat
        flash_attn<<<dim3(S/128, BATCH*NH), 256, 0, stream>>>(qkvf, vt, zf);

        // attn_out = z_flat @ W_O^T, fused residual add into x
        gemm_tn<64,128,2,false,false><<<dim3(MTOK/64, DM/128, 1), 256, 0, stream>>>(
            zf, 0L, wo + (long)l*DM*DM, 0L, nullptr, 0L, DM,
            nullptr, xf, xb, DM);
        // MLP in: relu(x @ W_in^T + b_in): 256x256 pipelined kernel
        gemm256<0,true,true><<<dim3(MTOK/256, DMLP/256), 512, 0, stream>>>(
            xb, win + (long)l*DMLP*DM, (char*)post, DMLP,
            b_in + (long)l*DMLP, DM);
        // MLP out + b_out, fused residual add into x
        gemm_tn<64,128,2,true,false><<<dim3(MTOK/64, DM/128, 1), 256, 0, stream>>>(
            post, 0L, wout + (long)l*DM*DMLP, 0L, nullptr, 0L, DM,
            b_out + (long)l*DM, xf, xb, DMLP);
    }

    // logits = x @ W_U  (f32 out): 256x256 pipelined kernel
    gemm256<1,false,false><<<dim3(MTOK/256, DV/256), 512, 0, stream>>>(
        xb, wut, (char*)out, DV, nullptr, DM);
}